// Round 16
// baseline (1176.461 us; speedup 1.0000x reference)
//
#include <hip/hip_runtime.h>
#include <hip/hip_bf16.h>
#include <cstdint>
#include <cstddef>

#define NB 16
#define NN 8192
#define NS 512
#define NK 32
#define NG (NB*NS)          // 8192 groups
#define GPB 4               // groups per pass-block
#define NBLK (NG/GPB)       // 2048
#define NPOSI 262144        // NG*NK positions

// float64 squared distance, numpy order ((dx*dx + dy*dy) + dz*dz), no contraction.
__device__ __forceinline__ double sq3d(double dx, double dy, double dz){
#pragma clang fp contract(off)
  const double a = dx*dx;
  const double b = dy*dy;
  const double c = dz*dz;
  return (a + b) + c;
}

// one DPP-max step on a u32 (nonneg-float bitpattern: u32 order == float order)
template<int CTRL>
__device__ __forceinline__ unsigned dpp_umax_step(unsigned v){
  const unsigned o = (unsigned)__builtin_amdgcn_update_dpp(0, (int)v, CTRL, 0xf, 0xf, false);
  return v > o ? v : o;
}
// full-wave (64-lane) max; result valid in lane 63
__device__ __forceinline__ unsigned wave_umax63(unsigned v){
  v = dpp_umax_step<0xB1>(v);    // quad_perm xor1
  v = dpp_umax_step<0x4E>(v);    // quad_perm xor2
  v = dpp_umax_step<0x141>(v);   // row_half_mirror
  v = dpp_umax_step<0x140>(v);   // row_mirror
  v = dpp_umax_step<0x142>(v);   // row_bcast15
  v = dpp_umax_step<0x143>(v);   // row_bcast31 -> lane63 complete
  return v;
}
// max within each 16-lane group, result in ALL lanes of the group
__device__ __forceinline__ unsigned grp16_umax(unsigned v){
  v = dpp_umax_step<0xB1>(v);
  v = dpp_umax_step<0x4E>(v);
  v = dpp_umax_step<0x141>(v);
  v = dpp_umax_step<0x140>(v);
  return v;
}

// spread 4 bits to positions 0,3,6,9
__device__ __forceinline__ unsigned mort4(unsigned v){
  return (v & 1u) | ((v & 2u) << 2) | ((v & 4u) << 4) | ((v & 8u) << 6);
}

// ---------------- one-time Morton bucketing: ord[b][pos] = original index ----------------
__global__ __launch_bounds__(1024) void k_morton(const float* __restrict__ xyz,
                                                 int* __restrict__ ord){
  const int b = blockIdx.x;
  const int t = threadIdx.x;
  const float* __restrict__ X = xyz + (size_t)b*NN*3;
  __shared__ unsigned sHist[4096];
  __shared__ unsigned sWT[16];
  for (int k=t; k<4096; k+=1024) sHist[k] = 0u;
  __syncthreads();
  unsigned code[8];
#pragma unroll
  for (int j=0;j<8;++j){
    const int p = t + 1024*j;
    const float x=X[p*3+0], y=X[p*3+1], z=X[p*3+2];
    const unsigned ix=(unsigned)min(15,max(0,(int)(x*16.f)));
    const unsigned iy=(unsigned)min(15,max(0,(int)(y*16.f)));
    const unsigned iz=(unsigned)min(15,max(0,(int)(z*16.f)));
    code[j] = mort4(ix) | (mort4(iy)<<1) | (mort4(iz)<<2);
    atomicAdd(&sHist[code[j]], 1u);
  }
  __syncthreads();
  // exclusive scan over 4096 bins (thread owns 4 bins)
  {
    const uint4 h = ((const uint4*)sHist)[t];
    const unsigned l1=h.x, l2=h.x+h.y, l3=h.x+h.y+h.z, tot=l3+h.w;
    unsigned inc = tot;
    const int lane = t & 63;
#pragma unroll
    for (int d2=1; d2<64; d2<<=1){
      const unsigned v = __shfl_up(inc, d2);
      if (lane >= d2) inc += v;
    }
    const unsigned wexc = inc - tot;
    if (lane == 63) sWT[t>>6] = inc;
    __syncthreads();
    if (t == 0){
      unsigned run = 0;
#pragma unroll
      for (int k=0;k<16;++k){ const unsigned v=sWT[k]; sWT[k]=run; run+=v; }
    }
    __syncthreads();
    const unsigned base = sWT[t>>6] + wexc;
    uint4 o; o.x=base; o.y=base+l1; o.z=base+l2; o.w=base+l3;
    ((uint4*)sHist)[t] = o;
  }
  __syncthreads();
#pragma unroll
  for (int j=0;j<8;++j){
    const unsigned pos = atomicAdd(&sHist[code[j]], 1u);
    ord[(size_t)b*NN + pos] = t + 1024*j;
  }
}

// ---------------- FPS: flat 1-hop handshake + sleep-throttled poll + cached publish ----
// Exactness invariants (numpy-f64-bit-exact), proven earlier rounds:
//  * dd[j] exact f64 min sq-dist (numpy order); screen thr=dd32*(1+2^-19) conservative;
//    Morton thread-skip margins conservative (R9/R12).
//  * wave winner: f32 DPP max -> ballot -> exact (f64,min-orig-idx) writer (R10);
//    CACHED when no lane updated this iteration (bit-identical by invariance).
//  * block winner: lanes poll packed {wf32,tag,idx} (slot=lane&15, x4 replicated);
//    grp16 DPP f32 max = candidate superset (RN monotone); unique slot (popc==4) ->
//    readlane idx; ties -> exact f64 side-slot resolve (max val, min orig idx).
// Sync: release publish; readers 1-read/lane poll (s_sleep-throttled retries) +
// acquire fence. Parity dbuf, max skew 1 iter.
__global__ __launch_bounds__(1024) void k_fps(const float* __restrict__ xyz,
                                              const int* __restrict__ ord,
                                              float* __restrict__ newxyz){
  const int b = blockIdx.x;
  const int t = threadIdx.x;
  const float* __restrict__ X = xyz + (size_t)b*NN*3;

  __shared__ float4 sP[NN];                      // 128 KB, original index order
  __shared__ unsigned long long sW0[2][16];      // packed {wf:32 | (i+1)<<13 | idx:13}
  __shared__ unsigned long long sWv64[2][16];    // exact f64 bits (side slot)

  int oidx[8];
#pragma unroll
  for (int j=0;j<8;++j){
    const int p = t + 1024*j;
    sP[p] = make_float4(X[p*3+0], X[p*3+1], X[p*3+2], 0.f);
    oidx[j] = ord[(size_t)b*NN + 8*t + j];
  }
  if (t < 16){ sW0[0][t]=0ull; sW0[1][t]=0ull; }
  __syncthreads();     // only barrier

  float px[8], py[8], pz[8], thr[8];
  double dd[8];
#pragma unroll
  for (int j=0;j<8;++j){
    const float4 q = sP[oidx[j]];
    px[j]=q.x; py[j]=q.y; pz[j]=q.z;
    dd[j]=1e10;
    thr[j]=fmaf(1e10f, 0x1p-19f, 1e10f);
  }
  // bounding sphere of owned (Morton-adjacent) points, conservative margins
  float ctx=0.f, cty=0.f, ctz=0.f;
#pragma unroll
  for (int j=0;j<8;++j){ ctx+=px[j]; cty+=py[j]; ctz+=pz[j]; }
  ctx*=0.125f; cty*=0.125f; ctz*=0.125f;
  float r2m = 0.f;
#pragma unroll
  for (int j=0;j<8;++j){
    const float ax=px[j]-ctx, ay=py[j]-cty, az=pz[j]-ctz;
    r2m = fmaxf(r2m, fmaf(az,az,fmaf(ay,ay,ax*ax)));
  }
  const float rT = sqrtf(r2m)*(1.0f+0x1p-18f) + 0x1p-20f;

  double tmax = 1e10;
  float  tmax32 = 1e10f;
  int tio = oidx[0], ts = 0;
#pragma unroll
  for (int j=1;j<8;++j) if (oidx[j] < tio){ tio = oidx[j]; ts = j; }
  float skipgate = tmax32*(1.0f+0x1p-14f);

  int f = 0;
  const int lane = t & 63, wid = t >> 6;
  unsigned long long pk_c = 0ull, wv64_c = 0ull;   // cached wave-winner publish words

  for (int i=0;i<NS-1;++i){
    const int par = i & 1;
    const float4 cf = sP[f];                 // uniform LDS broadcast
    const float cx=cf.x, cy=cf.y, cz=cf.z;
    if (t == 0){                             // fire-and-forget centroid store
      float* o = newxyz + ((size_t)b*NS + i)*3;
      o[0]=cx; o[1]=cy; o[2]=cz;
    }

    // ---- thread-level conservative skip ----
    const float bx=cx-ctx, by=cy-cty, bz=cz-ctz;
    const float ddc = fmaf(bz,bz,fmaf(by,by,bx*bx));
    const float dcc = sqrtf(ddc);
    float s = dcc - rT; s = s - dcc*0x1p-16f;
    const bool engage = !(s > 0.f && s*s >= skipgate);

    bool lane_changed = false;
    if (engage){
      float e[8]; float mmin = 1e30f;
#pragma unroll
      for (int j=0;j<8;++j){
        const float ax=px[j]-cx, ay=py[j]-cy, az=pz[j]-cz;
        const float d32 = fmaf(az, az, fmaf(ay, ay, ax*ax));
        e[j] = d32 - thr[j];
        mmin = fminf(mmin, e[j]);
      }
      if (__builtin_expect(mmin <= 0.f, 0)){
        const double cxd=(double)cx, cyd=(double)cy, czd=(double)cz;
        bool needscan = false;
#pragma unroll
        for (int j=0;j<8;++j){
          if (e[j] <= 0.f){
            const double d64 = sq3d((double)px[j]-cxd, (double)py[j]-cyd, (double)pz[j]-czd);
            const double nd = fmin(dd[j], d64);
            needscan |= (j == ts) | (nd == tmax);
            dd[j] = nd;
            const float nd32 = (float)nd;
            thr[j] = fmaf(nd32, 0x1p-19f, nd32);
          }
        }
        if (needscan){
          double tm = dd[0]; int io = oidx[0]; int s0 = 0;
#pragma unroll
          for (int j=1;j<8;++j)
            if (dd[j] > tm || (dd[j] == tm && oidx[j] < io)){ tm=dd[j]; io=oidx[j]; s0=j; }
          tmax=tm; tio=io; ts=s0; tmax32=(float)tm;
          skipgate = tmax32*(1.0f+0x1p-14f);
          lane_changed = true;
        }
      }
    }

    // ---- wave winner: full path only if some lane changed (else cached) ----
    const unsigned long long chm = __ballot(lane_changed);
    if (chm != 0ull || i == 0){
      const unsigned myb = __float_as_uint(tmax32);
      const unsigned wmx = (unsigned)__builtin_amdgcn_readlane((int)wave_umax63(myb), 63);
      const unsigned long long mask = __ballot(myb == wmx);
      int writer;
      if (__builtin_expect(__popcll(mask) == 1, 1)){
        writer = (int)__builtin_ctzll(mask);
      } else {
        double bestv = -1.0; int bestid = 0x7fffffff;
        unsigned long long mm = mask;
        while (mm){
          const int l = (int)__builtin_ctzll(mm);
          const double v = __shfl(tmax, l);
          const int   id = __shfl(tio, l);
          if (v > bestv || (v == bestv && id < bestid)){ bestv=v; bestid=id; }
          mm &= mm - 1;
        }
        writer = (int)__builtin_ctzll(__ballot(tmax == bestv && tio == bestid));
      }
      // broadcast winner to all lanes; refresh cache (bit-exact wave state)
      wv64_c = (unsigned long long)__double_as_longlong(__shfl(tmax, writer));
      pk_c   = ((unsigned long long)wmx << 32)
             | (unsigned long long)(unsigned)__shfl(tio, writer);
    }
    if (lane == 0){
      sWv64[par][wid] = wv64_c;
      __hip_atomic_store(&sW0[par][wid],
                         pk_c | ((unsigned long long)(unsigned)(i+1) << 13),
                         __ATOMIC_RELEASE, __HIP_MEMORY_SCOPE_WORKGROUP);
    }

    // ---- flat block reduce: 1 b64 read/lane/poll, sleep-throttled retries ----
    const unsigned want = (unsigned)(i+1);
    unsigned long long w = __hip_atomic_load(&sW0[par][lane & 15],
                           __ATOMIC_RELAXED, __HIP_MEMORY_SCOPE_WORKGROUP);
    while (__ballot((((unsigned)w >> 13) & 1023u) == want) != ~0ull){
      __builtin_amdgcn_s_sleep(1);
      w = __hip_atomic_load(&sW0[par][lane & 15],
                            __ATOMIC_RELAXED, __HIP_MEMORY_SCOPE_WORKGROUP);
    }
    __builtin_amdgcn_fence(__ATOMIC_ACQUIRE, "workgroup");

    const unsigned wf   = (unsigned)(w >> 32);
    const unsigned idxw = (unsigned)w & 8191u;
    const unsigned m32  = grp16_umax(wf);          // block max, all lanes
    const unsigned long long cm = __ballot(wf == m32);
    if (__builtin_expect(__popcll(cm) == 4, 1)){   // unique slot (x4 replicas)
      f = __shfl((int)idxw, (int)__builtin_ctzll(cm));
    } else {
      // rare: exact f64 resolve among f32-bit-tied slots (max value, min index)
      unsigned long long mm = cm & 0xFFFFull;      // one replica set
      double bv = -1.0; int bid = 0x7fffffff;
      while (mm){
        const int l = (int)__builtin_ctzll(mm);
        const double v = __longlong_as_double((long long)sWv64[par][l]); // uniform bcast
        const int   id = __shfl((int)idxw, l);
        if (v > bv || (v == bv && id < bid)){ bv = v; bid = id; }
        mm &= mm - 1;
      }
      f = bid;
    }
  }
  // last centroid
  if (t == 0){
    const float4 cf = sP[f];
    float* o = newxyz + ((size_t)b*NS + (NS-1))*3;
    o[0]=cf.x; o[1]=cf.y; o[2]=cf.z;
  }
}

// ---------------- Ball query: one wave per centroid, f32 screen + f64 band ----------------
__global__ __launch_bounds__(256) void k_ball(const float* __restrict__ xyz,
                                              const float* __restrict__ newxyz,
                                              int* __restrict__ idx){
  const int w = (blockIdx.x << 2) + (threadIdx.x >> 6);  // group id = b*NS+s
  const int lane = threadIdx.x & 63;
  const int b = w >> 9;
  const float* __restrict__ C = newxyz + (size_t)w*3;
  const float cxf=C[0], cyf=C[1], czf=C[2];
  const double cx=(double)cxf, cy=(double)cyf, cz=(double)czf;
  const float* __restrict__ X = xyz + (size_t)b*NN*3;
  int* __restrict__ out = idx + (size_t)w*NK;
  const double R2 = 0.2*0.2;                   // f64: 0.04000000000000000083...
  const float r2lo = 0.04f*(1.0f - 0x1p-16f);  // certain-in  below
  const float r2hi = 0.04f*(1.0f + 0x1p-16f);  // certain-out above
  int count = 0, first = 0;
  for (int base=0; base<NN && count<NK; base+=64){
    const int p = base + lane;
    const float ax=X[p*3+0]-cxf, ay=X[p*3+1]-cyf, az=X[p*3+2]-czf;
    const float d32 = fmaf(az, az, fmaf(ay, ay, ax*ax));
    bool q;
    if (d32 <= r2lo)      q = true;
    else if (d32 > r2hi)  q = false;
    else {                                     // rare band: exact f64 decision
      const double d = sq3d((double)X[p*3+0]-cx, (double)X[p*3+1]-cy, (double)X[p*3+2]-cz);
      q = !(d > R2);
    }
    const unsigned long long m = __ballot(q);
    if (q){
      const int pos = count + __popcll(m & ((1ull<<lane)-1ull));
      if (pos < NK) out[pos] = p;
    }
    if (count == 0 && m) first = base + __builtin_ctzll(m);
    count += __popcll(m);
  }
  if (lane >= count && lane < NK) out[lane] = first;   // pad with first index
}

// ---------------- per-block stats (+optional group min/max) reduction ----------------
__device__ __forceinline__ void stats_reduce(
    float v[4][8], float* __restrict__ sRed, int t, int tp, int tc, int blk,
    int chtot, int choff, bool domm,
    float* __restrict__ pS, float* __restrict__ pQ,
    float* __restrict__ mxp, float* __restrict__ mnp)
{
  __syncthreads();   // sRed overlays sX0/sW0/sV — ensure all prior reads done
  float S=0.f, Q=0.f;
  for (int m=0;m<4;++m){
#pragma unroll
    for (int i=0;i<8;++i) sRed[tp*68 + tc*8 + i] = v[m][i];
    __syncthreads();
    if (t < 64){
      float mxv = -3.402823466e38f, mnv = 3.402823466e38f;
#pragma unroll
      for (int j=0;j<32;++j){
        const float x = sRed[j*68 + t];
        S += x; Q += x*x;
        mxv = fmaxf(mxv,x); mnv = fminf(mnv,x);
      }
      if (domm){
        const int gg = blk*GPB + m;
        mxp[(size_t)gg*128 + choff + t] = mxv;
        mnp[(size_t)gg*128 + choff + t] = mnv;
      }
    }
    __syncthreads();
  }
  if (t < 64){
    pS[(size_t)blk*chtot + choff + t] = S;
    pQ[(size_t)blk*chtot + choff + t] = Q;
  }
}

// 64-deep inner product accumulate: v[m][i] += sX[pos_m][k]*sW[ch_i][k]
__device__ __forceinline__ void mm64(const float* __restrict__ sXl,
                                     const float* __restrict__ sWl,
                                     int tp, int tc, float v[4][8]){
#pragma unroll 4
  for (int k=0;k<64;++k){
    float xv[4], wv[8];
#pragma unroll
    for (int m=0;m<4;++m) xv[m] = sXl[(tp+32*m)*65 + k];
#pragma unroll
    for (int i=0;i<8;++i) wv[i] = sWl[(tc*8+i)*65 + k];
#pragma unroll
    for (int m=0;m<4;++m)
#pragma unroll
      for (int i=0;i<8;++i) v[m][i] += xv[m]*wv[i];
  }
}

// ---------------- MLP pass: recompute chain to layer DEPTH, emit stats ----------------
template<int DEPTH>
__global__ __launch_bounds__(256) void k_pass(
    const float* __restrict__ xyz, const float* __restrict__ points,
    const float* __restrict__ newxyz, const int* __restrict__ idx,
    const float* __restrict__ w0, const float* __restrict__ b0,
    const float* __restrict__ w1, const float* __restrict__ b1,
    const float* __restrict__ w2, const float* __restrict__ b2,
    const float* __restrict__ ac,
    float* __restrict__ pS, float* __restrict__ pQ,
    float* __restrict__ mxp, float* __restrict__ mnp)
{
  __shared__ float smem[(DEPTH>=1) ? 14784 : 2304];
  float* sX0 = smem;
  float* sW0 = smem + 1024;
  float* sV  = smem + 1600;
  float* sRed= smem;            // overlay
  float* sB2 = smem + 2176;
  float* sW1 = smem + 2304;
  float* sX  = smem + 6464;

  const int t = threadIdx.x;
  const int blk = blockIdx.x;
  const int tc = t & 7, tp = t >> 3;

  // stage weights / params
  for (int i=t;i<384;i+=256) sW0[(i/6)*9 + (i%6)] = w0[i];
  if (t < 64) sV[t] = b0[t];
  if constexpr (DEPTH >= 1){
    if (t < 64){ sV[64+t]=ac[t]; sV[128+t]=ac[64+t]; sV[192+t]=b1[t]; }
    for (int i=t;i<4096;i+=256) sW1[(i>>6)*65 + (i&63)] = w1[i];
  }
  if constexpr (DEPTH == 2){
    if (t < 64){ sV[256+t]=ac[128+t]; sV[320+t]=ac[192+t]; }
    if (t < 128) sB2[t] = b2[t];
  }

  // gather -> x0 (6 ch): [gxyz - centroid, gpts]
  {
    const int pos = t & 127;
    const int gg = blk*GPB + (pos >> 5);
    const int b  = gg >> 9;
    const int id = idx[gg*NK + (pos & 31)];
    if (t < 128){
      const float* __restrict__ P = xyz + ((size_t)b*NN + id)*3;
      const float* __restrict__ C = newxyz + (size_t)gg*3;
      sX0[pos*8+0] = P[0]-C[0];
      sX0[pos*8+1] = P[1]-C[1];
      sX0[pos*8+2] = P[2]-C[2];
    } else {
      const float* __restrict__ P = points + ((size_t)b*NN + id)*3;
      sX0[pos*8+3] = P[0];
      sX0[pos*8+4] = P[1];
      sX0[pos*8+5] = P[2];
    }
  }
  __syncthreads();

  // y0 = W0 x0 + b0   (thread: 4 positions x 8 channels)
  float v[4][8];
#pragma unroll
  for (int m=0;m<4;++m){
    const int pos = tp + 32*m;
    float xr[6];
#pragma unroll
    for (int c=0;c<6;++c) xr[c] = sX0[pos*8+c];
#pragma unroll
    for (int i=0;i<8;++i){
      const int ch = tc*8+i;
      float acc = sV[ch];
#pragma unroll
      for (int c=0;c<6;++c) acc += sW0[ch*9+c]*xr[c];
      v[m][i] = acc;
    }
  }

  if constexpr (DEPTH == 0){
    stats_reduce(v, sRed, t, tp, tc, blk, 64, 0, false, pS, pQ, mxp, mnp);
    return;
  } else {
    // x1 = relu(a0*y0 + c0)
#pragma unroll
    for (int m=0;m<4;++m){
      const int pos = tp + 32*m;
#pragma unroll
      for (int i=0;i<8;++i){
        const int ch = tc*8+i;
        sX[pos*65+ch] = fmaxf(sV[64+ch]*v[m][i] + sV[128+ch], 0.f);
      }
    }
    __syncthreads();
    // y1 = W1 x1 + b1
#pragma unroll
    for (int m=0;m<4;++m)
#pragma unroll
      for (int i=0;i<8;++i) v[m][i] = sV[192 + tc*8 + i];
    mm64(sX, sW1, tp, tc, v);

    if constexpr (DEPTH == 1){
      stats_reduce(v, sRed, t, tp, tc, blk, 64, 0, false, pS, pQ, mxp, mnp);
      return;
    } else {
      __syncthreads();
      // x2 = relu(a1*y1 + c1), overwrite sX
#pragma unroll
      for (int m=0;m<4;++m){
        const int pos = tp + 32*m;
#pragma unroll
        for (int i=0;i<8;++i){
          const int ch = tc*8+i;
          sX[pos*65+ch] = fmaxf(sV[256+ch]*v[m][i] + sV[320+ch], 0.f);
        }
      }
      __syncthreads();
      // y2 = W2 x2 + b2 in two 64-channel chunks (W2 chunk reuses sW1 space)
      for (int o=0;o<2;++o){
        for (int i=t;i<4096;i+=256) sW1[(i>>6)*65 + (i&63)] = w2[o*4096 + i];
        __syncthreads();
#pragma unroll
        for (int m=0;m<4;++m)
#pragma unroll
          for (int i=0;i<8;++i) v[m][i] = sB2[o*64 + tc*8 + i];
        mm64(sX, sW1, tp, tc, v);
        stats_reduce(v, sRed, t, tp, tc, blk, 128, o*64, true, pS, pQ, mxp, mnp);
      }
      return;
    }
  }
}

// ---------------- derive BN affine a,c: segmented 1024-thread reduce ----------------
__global__ __launch_bounds__(1024) void k_stats(const float* __restrict__ pS, const float* __restrict__ pQ,
                                                const float* __restrict__ g, const float* __restrict__ beta,
                                                float* __restrict__ a, float* __restrict__ c, int CH){
  __shared__ float sS[1024], sQ[1024];
  const int t = threadIdx.x;
  const int ch = t & (CH-1);
  const int seg = t / CH;
  const int SEG = 1024 / CH;          // 16 (CH=64) or 8 (CH=128)
  const int rows = NBLK / SEG;        // 128 or 256
  float S=0.f, Q=0.f;
  const int j0 = seg*rows;
#pragma unroll 4
  for (int r=0;r<rows;++r){
    const size_t o = (size_t)(j0+r)*CH + ch;
    S += pS[o]; Q += pQ[o];
  }
  sS[t]=S; sQ[t]=Q;
  __syncthreads();
  if (t < CH){
    float aS=0.f, aQ=0.f;
    for (int s2=0;s2<SEG;++s2){ aS += sS[s2*CH+ch]; aQ += sQ[s2*CH+ch]; }
    const float mean = aS * (1.f/(float)NPOSI);
    const float var  = fmaxf(aQ * (1.f/(float)NPOSI) - mean*mean, 0.f);
    const float av = g[ch] * rsqrtf(var + 1e-5f);
    a[ch] = av;
    c[ch] = beta[ch] - mean*av;
  }
}

// ---------------- final: BN+ReLU applied to pooled value ----------------
__global__ __launch_bounds__(256) void k_final(const float* __restrict__ mxp, const float* __restrict__ mnp,
                                               const float* __restrict__ a, const float* __restrict__ c,
                                               float* __restrict__ out){
  const int i = blockIdx.x*256 + threadIdx.x;
  const int ch = i & 127;
  const float av = a[ch], cv = c[ch];
  const float vv = (av >= 0.f) ? mxp[i] : mnp[i];   // relu∘affine is monotone
  out[i] = fmaxf(av*vv + cv, 0.f);
}

extern "C" void kernel_launch(void* const* d_in, const int* in_sizes, int n_in,
                              void* d_out, int out_size, void* d_ws, size_t ws_size,
                              hipStream_t stream){
  (void)in_sizes; (void)n_in; (void)out_size;
  const float* xyz    = (const float*)d_in[0];
  const float* points = (const float*)d_in[1];
  const float* w0 = (const float*)d_in[2];
  const float* b0 = (const float*)d_in[3];
  const float* g0 = (const float*)d_in[4];
  const float* be0= (const float*)d_in[5];
  const float* w1 = (const float*)d_in[6];
  const float* b1 = (const float*)d_in[7];
  const float* g1 = (const float*)d_in[8];
  const float* be1= (const float*)d_in[9];
  const float* w2 = (const float*)d_in[10];
  const float* b2 = (const float*)d_in[11];
  const float* g2 = (const float*)d_in[12];
  const float* be2= (const float*)d_in[13];

  float* out_newxyz = (float*)d_out;
  float* out_newpts = out_newxyz + (size_t)NB*NS*3;

  char* ws = (char*)d_ws;
  int*   idx = (int*)ws;                              // 1 MiB (ord overlays first 512KB, consumed before k_ball writes)
  float* ac  = (float*)(ws + (1u<<20));               // 512 floats
  float* pS  = (float*)(ws + (1u<<20) + 4096);        // 2048*128 f
  float* pQ  = pS + (size_t)NBLK*128;                 // 2048*128 f
  float* mxp = pQ + (size_t)NBLK*128;                 // 8192*128 f
  float* mnp = mxp + (size_t)NG*128;                  // 8192*128 f
  const size_t need = (1u<<20) + 4096 + (size_t)2*NBLK*128*4 + (size_t)2*NG*128*4;
  if (ws_size < need) return;  // ~11.5 MiB required

  int* ord = idx;   // reuse: written by k_morton, read by k_fps, then overwritten by k_ball

  k_morton<<<NB, 1024, 0, stream>>>(xyz, ord);
  k_fps  <<<NB, 1024, 0, stream>>>(xyz, ord, out_newxyz);
  k_ball <<<NG/4, 256, 0, stream>>>(xyz, out_newxyz, idx);

  k_pass<0><<<NBLK,256,0,stream>>>(xyz,points,out_newxyz,idx,w0,b0,w1,b1,w2,b2,ac,pS,pQ,mxp,mnp);
  k_stats<<<1,1024,0,stream>>>(pS,pQ,g0,be0, ac+0,   ac+64,  64);
  k_pass<1><<<NBLK,256,0,stream>>>(xyz,points,out_newxyz,idx,w0,b0,w1,b1,w2,b2,ac,pS,pQ,mxp,mnp);
  k_stats<<<1,1024,0,stream>>>(pS,pQ,g1,be1, ac+128, ac+192, 64);
  k_pass<2><<<NBLK,256,0,stream>>>(xyz,points,out_newxyz,idx,w0,b0,w1,b1,w2,b2,ac,pS,pQ,mxp,mnp);
  k_stats<<<1,1024,0,stream>>>(pS,pQ,g2,be2, ac+256, ac+384, 128);
  k_final<<<(NG*128)/256,256,0,stream>>>(mxp,mnp,ac+256,ac+384,out_newpts);
}

// Round 17
// 1029.760 us; speedup vs baseline: 1.1425x; 1.1425x over previous
//
#include <hip/hip_runtime.h>
#include <hip/hip_bf16.h>
#include <cstdint>
#include <cstddef>

#define NB 16
#define NN 8192
#define NS 512
#define NK 32
#define NG (NB*NS)          // 8192 groups
#define GPB 4               // groups per pass-block
#define NBLK (NG/GPB)       // 2048
#define NPOSI 262144        // NG*NK positions
#define SBLK 16             // stats stage-1 blocks

// float64 squared distance, numpy order ((dx*dx + dy*dy) + dz*dz), no contraction.
__device__ __forceinline__ double sq3d(double dx, double dy, double dz){
#pragma clang fp contract(off)
  const double a = dx*dx;
  const double b = dy*dy;
  const double c = dz*dz;
  return (a + b) + c;
}

// one DPP-max step on a u32 (nonneg-float bitpattern: u32 order == float order)
template<int CTRL>
__device__ __forceinline__ unsigned dpp_umax_step(unsigned v){
  const unsigned o = (unsigned)__builtin_amdgcn_update_dpp(0, (int)v, CTRL, 0xf, 0xf, false);
  return v > o ? v : o;
}
// full-wave (64-lane) max; result valid in lane 63
__device__ __forceinline__ unsigned wave_umax63(unsigned v){
  v = dpp_umax_step<0xB1>(v);    // quad_perm xor1
  v = dpp_umax_step<0x4E>(v);    // quad_perm xor2
  v = dpp_umax_step<0x141>(v);   // row_half_mirror
  v = dpp_umax_step<0x140>(v);   // row_mirror
  v = dpp_umax_step<0x142>(v);   // row_bcast15
  v = dpp_umax_step<0x143>(v);   // row_bcast31 -> lane63 complete
  return v;
}
// max within each 16-lane group, result in ALL lanes of the group
__device__ __forceinline__ unsigned grp16_umax(unsigned v){
  v = dpp_umax_step<0xB1>(v);
  v = dpp_umax_step<0x4E>(v);
  v = dpp_umax_step<0x141>(v);
  v = dpp_umax_step<0x140>(v);
  return v;
}

// spread 4 bits to positions 0,3,6,9
__device__ __forceinline__ unsigned mort4(unsigned v){
  return (v & 1u) | ((v & 2u) << 2) | ((v & 4u) << 4) | ((v & 8u) << 6);
}

// ---------------- one-time Morton bucketing: ord[b][pos] = original index ----------------
__global__ __launch_bounds__(1024) void k_morton(const float* __restrict__ xyz,
                                                 int* __restrict__ ord){
  const int b = blockIdx.x;
  const int t = threadIdx.x;
  const float* __restrict__ X = xyz + (size_t)b*NN*3;
  __shared__ unsigned sHist[4096];
  __shared__ unsigned sWT[16];
  for (int k=t; k<4096; k+=1024) sHist[k] = 0u;
  __syncthreads();
  unsigned code[8];
#pragma unroll
  for (int j=0;j<8;++j){
    const int p = t + 1024*j;
    const float x=X[p*3+0], y=X[p*3+1], z=X[p*3+2];
    const unsigned ix=(unsigned)min(15,max(0,(int)(x*16.f)));
    const unsigned iy=(unsigned)min(15,max(0,(int)(y*16.f)));
    const unsigned iz=(unsigned)min(15,max(0,(int)(z*16.f)));
    code[j] = mort4(ix) | (mort4(iy)<<1) | (mort4(iz)<<2);
    atomicAdd(&sHist[code[j]], 1u);
  }
  __syncthreads();
  // exclusive scan over 4096 bins (thread owns 4 bins)
  {
    const uint4 h = ((const uint4*)sHist)[t];
    const unsigned l1=h.x, l2=h.x+h.y, l3=h.x+h.y+h.z, tot=l3+h.w;
    unsigned inc = tot;
    const int lane = t & 63;
#pragma unroll
    for (int d2=1; d2<64; d2<<=1){
      const unsigned v = __shfl_up(inc, d2);
      if (lane >= d2) inc += v;
    }
    const unsigned wexc = inc - tot;
    if (lane == 63) sWT[t>>6] = inc;
    __syncthreads();
    if (t == 0){
      unsigned run = 0;
#pragma unroll
      for (int k=0;k<16;++k){ const unsigned v=sWT[k]; sWT[k]=run; run+=v; }
    }
    __syncthreads();
    const unsigned base = sWT[t>>6] + wexc;
    uint4 o; o.x=base; o.y=base+l1; o.z=base+l2; o.w=base+l3;
    ((uint4*)sHist)[t] = o;
  }
  __syncthreads();
#pragma unroll
  for (int j=0;j<8;++j){
    const unsigned pos = atomicAdd(&sHist[code[j]], 1u);
    ord[(size_t)b*NN + pos] = t + 1024*j;
  }
}

// ---------------- FPS: flat 1-hop handshake (1 read/lane/poll), exact argmax ----------------
// (Exact R15 structure — measured best 754 us.)
// Exactness invariants (numpy-f64-bit-exact), proven earlier rounds:
//  * dd[j] exact f64 min sq-dist (numpy order); screen thr=dd32*(1+2^-19) conservative;
//    Morton thread-skip margins conservative (R9/R12).
//  * wave winner: f32 DPP max -> ballot -> exact (f64,min-orig-idx) writer (R10).
//  * block winner: lanes poll packed {wf32,tag,idx} (slot=lane&15, x4 replicated);
//    grp16 DPP f32 max = candidate superset (RN monotone); unique slot (popc==4) ->
//    readlane idx; ties -> exact f64 side-slot resolve (max val, min orig idx).
// Sync: release publish; readers 1-read/lane poll + acquire fence. Parity dbuf,
// max skew 1 iter (publish i+2 requires consuming i+1 requires all i+1 publishes).
__global__ __launch_bounds__(1024) void k_fps(const float* __restrict__ xyz,
                                              const int* __restrict__ ord,
                                              float* __restrict__ newxyz){
  const int b = blockIdx.x;
  const int t = threadIdx.x;
  const float* __restrict__ X = xyz + (size_t)b*NN*3;

  __shared__ float4 sP[NN];                      // 128 KB, original index order
  __shared__ unsigned long long sW0[2][16];      // packed {wf:32 | (i+1)<<13 | idx:13}
  __shared__ unsigned long long sWv64[2][16];    // exact f64 bits (side slot)

  int oidx[8];
#pragma unroll
  for (int j=0;j<8;++j){
    const int p = t + 1024*j;
    sP[p] = make_float4(X[p*3+0], X[p*3+1], X[p*3+2], 0.f);
    oidx[j] = ord[(size_t)b*NN + 8*t + j];
  }
  if (t < 16){ sW0[0][t]=0ull; sW0[1][t]=0ull; }
  __syncthreads();     // only barrier

  float px[8], py[8], pz[8], thr[8];
  double dd[8];
#pragma unroll
  for (int j=0;j<8;++j){
    const float4 q = sP[oidx[j]];
    px[j]=q.x; py[j]=q.y; pz[j]=q.z;
    dd[j]=1e10;
    thr[j]=fmaf(1e10f, 0x1p-19f, 1e10f);
  }
  // bounding sphere of owned (Morton-adjacent) points, conservative margins
  float ctx=0.f, cty=0.f, ctz=0.f;
#pragma unroll
  for (int j=0;j<8;++j){ ctx+=px[j]; cty+=py[j]; ctz+=pz[j]; }
  ctx*=0.125f; cty*=0.125f; ctz*=0.125f;
  float r2m = 0.f;
#pragma unroll
  for (int j=0;j<8;++j){
    const float ax=px[j]-ctx, ay=py[j]-cty, az=pz[j]-ctz;
    r2m = fmaxf(r2m, fmaf(az,az,fmaf(ay,ay,ax*ax)));
  }
  const float rT = sqrtf(r2m)*(1.0f+0x1p-18f) + 0x1p-20f;

  double tmax = 1e10;
  float  tmax32 = 1e10f;
  int tio = oidx[0], ts = 0;
#pragma unroll
  for (int j=1;j<8;++j) if (oidx[j] < tio){ tio = oidx[j]; ts = j; }
  float skipgate = tmax32*(1.0f+0x1p-14f);

  int f = 0;
  const int lane = t & 63, wid = t >> 6;

  for (int i=0;i<NS-1;++i){
    const int par = i & 1;
    const float4 cf = sP[f];                 // uniform LDS broadcast
    const float cx=cf.x, cy=cf.y, cz=cf.z;
    if (t == 0){                             // fire-and-forget centroid store
      float* o = newxyz + ((size_t)b*NS + i)*3;
      o[0]=cx; o[1]=cy; o[2]=cz;
    }

    // ---- thread-level conservative skip ----
    const float bx=cx-ctx, by=cy-cty, bz=cz-ctz;
    const float ddc = fmaf(bz,bz,fmaf(by,by,bx*bx));
    const float dcc = sqrtf(ddc);
    float s = dcc - rT; s = s - dcc*0x1p-16f;
    const bool engage = !(s > 0.f && s*s >= skipgate);

    if (engage){
      float e[8]; float mmin = 1e30f;
#pragma unroll
      for (int j=0;j<8;++j){
        const float ax=px[j]-cx, ay=py[j]-cy, az=pz[j]-cz;
        const float d32 = fmaf(az, az, fmaf(ay, ay, ax*ax));
        e[j] = d32 - thr[j];
        mmin = fminf(mmin, e[j]);
      }
      if (__builtin_expect(mmin <= 0.f, 0)){
        const double cxd=(double)cx, cyd=(double)cy, czd=(double)cz;
        bool needscan = false;
#pragma unroll
        for (int j=0;j<8;++j){
          if (e[j] <= 0.f){
            const double d64 = sq3d((double)px[j]-cxd, (double)py[j]-cyd, (double)pz[j]-czd);
            const double nd = fmin(dd[j], d64);
            needscan |= (j == ts) | (nd == tmax);
            dd[j] = nd;
            const float nd32 = (float)nd;
            thr[j] = fmaf(nd32, 0x1p-19f, nd32);
          }
        }
        if (needscan){
          double tm = dd[0]; int io = oidx[0]; int s0 = 0;
#pragma unroll
          for (int j=1;j<8;++j)
            if (dd[j] > tm || (dd[j] == tm && oidx[j] < io)){ tm=dd[j]; io=oidx[j]; s0=j; }
          tmax=tm; tio=io; ts=s0; tmax32=(float)tm;
          skipgate = tmax32*(1.0f+0x1p-14f);
        }
      }
    }

    // ---- in-wave exact winner (f32 DPP + candidate resolve), single writer ----
    const unsigned myb = __float_as_uint(tmax32);
    const unsigned wm = (unsigned)__builtin_amdgcn_readlane((int)wave_umax63(myb), 63);
    const unsigned long long mask = __ballot(myb == wm);
    int writer;
    if (__builtin_expect(__popcll(mask) == 1, 1)){
      writer = (int)__builtin_ctzll(mask);
    } else {
      double bestv = -1.0; int bestid = 0x7fffffff;
      unsigned long long mm = mask;
      while (mm){
        const int l = (int)__builtin_ctzll(mm);
        const double v = __shfl(tmax, l);
        const int   id = __shfl(tio, l);
        if (v > bestv || (v == bestv && id < bestid)){ bestv=v; bestid=id; }
        mm &= mm - 1;
      }
      writer = (int)__builtin_ctzll(__ballot(tmax == bestv && tio == bestid));
    }
    if (lane == writer){
      sWv64[par][wid] = (unsigned long long)__double_as_longlong(tmax);
      const unsigned long long pk = ((unsigned long long)wm << 32)
                                  | ((unsigned long long)(unsigned)(i+1) << 13)
                                  | (unsigned long long)(unsigned)tio;
      __hip_atomic_store(&sW0[par][wid], pk,
                         __ATOMIC_RELEASE, __HIP_MEMORY_SCOPE_WORKGROUP);
    }

    // ---- flat block reduce: ONE b64 read per lane per poll round ----
    const unsigned want = (unsigned)(i+1);
    unsigned long long w;
    do {
      w = __hip_atomic_load(&sW0[par][lane & 15],
                            __ATOMIC_RELAXED, __HIP_MEMORY_SCOPE_WORKGROUP);
    } while (__ballot((((unsigned)w >> 13) & 1023u) == want) != ~0ull);
    __builtin_amdgcn_fence(__ATOMIC_ACQUIRE, "workgroup");

    const unsigned wf   = (unsigned)(w >> 32);
    const unsigned idxw = (unsigned)w & 8191u;
    const unsigned m32  = grp16_umax(wf);          // block max, all lanes
    const unsigned long long cm = __ballot(wf == m32);
    if (__builtin_expect(__popcll(cm) == 4, 1)){   // unique slot (x4 replicas)
      f = __shfl((int)idxw, (int)__builtin_ctzll(cm));
    } else {
      // rare: exact f64 resolve among f32-bit-tied slots (max value, min index)
      unsigned long long mm = cm & 0xFFFFull;      // one replica set
      double bv = -1.0; int bid = 0x7fffffff;
      while (mm){
        const int l = (int)__builtin_ctzll(mm);
        const double v = __longlong_as_double((long long)sWv64[par][l]); // uniform bcast
        const int   id = __shfl((int)idxw, l);
        if (v > bv || (v == bv && id < bid)){ bv = v; bid = id; }
        mm &= mm - 1;
      }
      f = bid;
    }
  }
  // last centroid
  if (t == 0){
    const float4 cf = sP[f];
    float* o = newxyz + ((size_t)b*NS + (NS-1))*3;
    o[0]=cf.x; o[1]=cf.y; o[2]=cf.z;
  }
}

// ---------------- Ball query: one wave per centroid, f32 screen + f64 band ----------------
__global__ __launch_bounds__(256) void k_ball(const float* __restrict__ xyz,
                                              const float* __restrict__ newxyz,
                                              int* __restrict__ idx){
  const int w = (blockIdx.x << 2) + (threadIdx.x >> 6);  // group id = b*NS+s
  const int lane = threadIdx.x & 63;
  const int b = w >> 9;
  const float* __restrict__ C = newxyz + (size_t)w*3;
  const float cxf=C[0], cyf=C[1], czf=C[2];
  const double cx=(double)cxf, cy=(double)cyf, cz=(double)czf;
  const float* __restrict__ X = xyz + (size_t)b*NN*3;
  int* __restrict__ out = idx + (size_t)w*NK;
  const double R2 = 0.2*0.2;                   // f64: 0.04000000000000000083...
  const float r2lo = 0.04f*(1.0f - 0x1p-16f);  // certain-in  below
  const float r2hi = 0.04f*(1.0f + 0x1p-16f);  // certain-out above
  int count = 0, first = 0;
  for (int base=0; base<NN && count<NK; base+=64){
    const int p = base + lane;
    const float ax=X[p*3+0]-cxf, ay=X[p*3+1]-cyf, az=X[p*3+2]-czf;
    const float d32 = fmaf(az, az, fmaf(ay, ay, ax*ax));
    bool q;
    if (d32 <= r2lo)      q = true;
    else if (d32 > r2hi)  q = false;
    else {                                     // rare band: exact f64 decision
      const double d = sq3d((double)X[p*3+0]-cx, (double)X[p*3+1]-cy, (double)X[p*3+2]-cz);
      q = !(d > R2);
    }
    const unsigned long long m = __ballot(q);
    if (q){
      const int pos = count + __popcll(m & ((1ull<<lane)-1ull));
      if (pos < NK) out[pos] = p;
    }
    if (count == 0 && m) first = base + __builtin_ctzll(m);
    count += __popcll(m);
  }
  if (lane >= count && lane < NK) out[lane] = first;   // pad with first index
}

// ---------------- per-block stats (+optional group min/max) reduction ----------------
__device__ __forceinline__ void stats_reduce(
    float v[4][8], float* __restrict__ sRed, int t, int tp, int tc, int blk,
    int chtot, int choff, bool domm,
    float* __restrict__ pS, float* __restrict__ pQ,
    float* __restrict__ mxp, float* __restrict__ mnp)
{
  __syncthreads();   // sRed overlays sX0/sW0/sV — ensure all prior reads done
  float S=0.f, Q=0.f;
  for (int m=0;m<4;++m){
#pragma unroll
    for (int i=0;i<8;++i) sRed[tp*68 + tc*8 + i] = v[m][i];
    __syncthreads();
    if (t < 64){
      float mxv = -3.402823466e38f, mnv = 3.402823466e38f;
#pragma unroll
      for (int j=0;j<32;++j){
        const float x = sRed[j*68 + t];
        S += x; Q += x*x;
        mxv = fmaxf(mxv,x); mnv = fminf(mnv,x);
      }
      if (domm){
        const int gg = blk*GPB + m;
        mxp[(size_t)gg*128 + choff + t] = mxv;
        mnp[(size_t)gg*128 + choff + t] = mnv;
      }
    }
    __syncthreads();
  }
  if (t < 64){
    pS[(size_t)blk*chtot + choff + t] = S;
    pQ[(size_t)blk*chtot + choff + t] = Q;
  }
}

// 64-deep inner product accumulate: v[m][i] += sX[pos_m][k]*sW[ch_i][k]
__device__ __forceinline__ void mm64(const float* __restrict__ sXl,
                                     const float* __restrict__ sWl,
                                     int tp, int tc, float v[4][8]){
#pragma unroll 4
  for (int k=0;k<64;++k){
    float xv[4], wv[8];
#pragma unroll
    for (int m=0;m<4;++m) xv[m] = sXl[(tp+32*m)*65 + k];
#pragma unroll
    for (int i=0;i<8;++i) wv[i] = sWl[(tc*8+i)*65 + k];
#pragma unroll
    for (int m=0;m<4;++m)
#pragma unroll
      for (int i=0;i<8;++i) v[m][i] += xv[m]*wv[i];
  }
}

// ---------------- MLP pass: recompute chain to layer DEPTH, emit stats ----------------
template<int DEPTH>
__global__ __launch_bounds__(256) void k_pass(
    const float* __restrict__ xyz, const float* __restrict__ points,
    const float* __restrict__ newxyz, const int* __restrict__ idx,
    const float* __restrict__ w0, const float* __restrict__ b0,
    const float* __restrict__ w1, const float* __restrict__ b1,
    const float* __restrict__ w2, const float* __restrict__ b2,
    const float* __restrict__ ac,
    float* __restrict__ pS, float* __restrict__ pQ,
    float* __restrict__ mxp, float* __restrict__ mnp)
{
  __shared__ float smem[(DEPTH>=1) ? 14784 : 2304];
  float* sX0 = smem;
  float* sW0 = smem + 1024;
  float* sV  = smem + 1600;
  float* sRed= smem;            // overlay
  float* sB2 = smem + 2176;
  float* sW1 = smem + 2304;
  float* sX  = smem + 6464;

  const int t = threadIdx.x;
  const int blk = blockIdx.x;
  const int tc = t & 7, tp = t >> 3;

  // stage weights / params
  for (int i=t;i<384;i+=256) sW0[(i/6)*9 + (i%6)] = w0[i];
  if (t < 64) sV[t] = b0[t];
  if constexpr (DEPTH >= 1){
    if (t < 64){ sV[64+t]=ac[t]; sV[128+t]=ac[64+t]; sV[192+t]=b1[t]; }
    for (int i=t;i<4096;i+=256) sW1[(i>>6)*65 + (i&63)] = w1[i];
  }
  if constexpr (DEPTH == 2){
    if (t < 64){ sV[256+t]=ac[128+t]; sV[320+t]=ac[192+t]; }
    if (t < 128) sB2[t] = b2[t];
  }

  // gather -> x0 (6 ch): [gxyz - centroid, gpts]
  {
    const int pos = t & 127;
    const int gg = blk*GPB + (pos >> 5);
    const int b  = gg >> 9;
    const int id = idx[gg*NK + (pos & 31)];
    if (t < 128){
      const float* __restrict__ P = xyz + ((size_t)b*NN + id)*3;
      const float* __restrict__ C = newxyz + (size_t)gg*3;
      sX0[pos*8+0] = P[0]-C[0];
      sX0[pos*8+1] = P[1]-C[1];
      sX0[pos*8+2] = P[2]-C[2];
    } else {
      const float* __restrict__ P = points + ((size_t)b*NN + id)*3;
      sX0[pos*8+3] = P[0];
      sX0[pos*8+4] = P[1];
      sX0[pos*8+5] = P[2];
    }
  }
  __syncthreads();

  // y0 = W0 x0 + b0   (thread: 4 positions x 8 channels)
  float v[4][8];
#pragma unroll
  for (int m=0;m<4;++m){
    const int pos = tp + 32*m;
    float xr[6];
#pragma unroll
    for (int c=0;c<6;++c) xr[c] = sX0[pos*8+c];
#pragma unroll
    for (int i=0;i<8;++i){
      const int ch = tc*8+i;
      float acc = sV[ch];
#pragma unroll
      for (int c=0;c<6;++c) acc += sW0[ch*9+c]*xr[c];
      v[m][i] = acc;
    }
  }

  if constexpr (DEPTH == 0){
    stats_reduce(v, sRed, t, tp, tc, blk, 64, 0, false, pS, pQ, mxp, mnp);
    return;
  } else {
    // x1 = relu(a0*y0 + c0)
#pragma unroll
    for (int m=0;m<4;++m){
      const int pos = tp + 32*m;
#pragma unroll
      for (int i=0;i<8;++i){
        const int ch = tc*8+i;
        sX[pos*65+ch] = fmaxf(sV[64+ch]*v[m][i] + sV[128+ch], 0.f);
      }
    }
    __syncthreads();
    // y1 = W1 x1 + b1
#pragma unroll
    for (int m=0;m<4;++m)
#pragma unroll
      for (int i=0;i<8;++i) v[m][i] = sV[192 + tc*8 + i];
    mm64(sX, sW1, tp, tc, v);

    if constexpr (DEPTH == 1){
      stats_reduce(v, sRed, t, tp, tc, blk, 64, 0, false, pS, pQ, mxp, mnp);
      return;
    } else {
      __syncthreads();
      // x2 = relu(a1*y1 + c1), overwrite sX
#pragma unroll
      for (int m=0;m<4;++m){
        const int pos = tp + 32*m;
#pragma unroll
        for (int i=0;i<8;++i){
          const int ch = tc*8+i;
          sX[pos*65+ch] = fmaxf(sV[256+ch]*v[m][i] + sV[320+ch], 0.f);
        }
      }
      __syncthreads();
      // y2 = W2 x2 + b2 in two 64-channel chunks (W2 chunk reuses sW1 space)
      for (int o=0;o<2;++o){
        for (int i=t;i<4096;i+=256) sW1[(i>>6)*65 + (i&63)] = w2[o*4096 + i];
        __syncthreads();
#pragma unroll
        for (int m=0;m<4;++m)
#pragma unroll
          for (int i=0;i<8;++i) v[m][i] = sB2[o*64 + tc*8 + i];
        mm64(sX, sW1, tp, tc, v);
        stats_reduce(v, sRed, t, tp, tc, blk, 128, o*64, true, pS, pQ, mxp, mnp);
      }
      return;
    }
  }
}

// ---------------- stats stage 1: 16 blocks, each sums NBLK/16 partial rows ----------------
__global__ __launch_bounds__(1024) void k_stats1(const float* __restrict__ pS,
                                                 const float* __restrict__ pQ,
                                                 float* __restrict__ pP, int CH){
  __shared__ float sS[1024], sQ[1024];
  const int t = threadIdx.x, blk = blockIdx.x;
  const int ch = t & (CH-1);
  const int seg = t / CH;
  const int SEG = 1024 / CH;                 // 16 (CH=64) or 8 (CH=128)
  const int rows = (NBLK/SBLK) / SEG;        // 8 or 16
  const int j0 = blk*(NBLK/SBLK) + seg*rows;
  float S=0.f, Q=0.f;
#pragma unroll 4
  for (int r=0;r<rows;++r){
    const size_t o = (size_t)(j0+r)*CH + ch;
    S += pS[o]; Q += pQ[o];
  }
  sS[t]=S; sQ[t]=Q;
  __syncthreads();
  if (t < CH){
    float aS=0.f, aQ=0.f;
    for (int s2=0;s2<SEG;++s2){ aS += sS[s2*CH+ch]; aQ += sQ[s2*CH+ch]; }
    pP[(size_t)blk*2*CH + ch]      = aS;
    pP[(size_t)blk*2*CH + CH + ch] = aQ;
  }
}

// ---------------- stats stage 2: fold 16 partials, derive a,c ----------------
__global__ __launch_bounds__(128) void k_stats2(const float* __restrict__ pP,
                                                const float* __restrict__ g,
                                                const float* __restrict__ beta,
                                                float* __restrict__ a, float* __restrict__ c,
                                                int CH){
  const int ch = threadIdx.x;
  if (ch >= CH) return;
  float S=0.f, Q=0.f;
#pragma unroll
  for (int k=0;k<SBLK;++k){
    S += pP[(size_t)k*2*CH + ch];
    Q += pP[(size_t)k*2*CH + CH + ch];
  }
  const float mean = S * (1.f/(float)NPOSI);
  const float var  = fmaxf(Q * (1.f/(float)NPOSI) - mean*mean, 0.f);
  const float av = g[ch] * rsqrtf(var + 1e-5f);
  a[ch] = av;
  c[ch] = beta[ch] - mean*av;
}

// ---------------- final: BN+ReLU applied to pooled value ----------------
__global__ __launch_bounds__(256) void k_final(const float* __restrict__ mxp, const float* __restrict__ mnp,
                                               const float* __restrict__ a, const float* __restrict__ c,
                                               float* __restrict__ out){
  const int i = blockIdx.x*256 + threadIdx.x;
  const int ch = i & 127;
  const float av = a[ch], cv = c[ch];
  const float vv = (av >= 0.f) ? mxp[i] : mnp[i];   // relu∘affine is monotone
  out[i] = fmaxf(av*vv + cv, 0.f);
}

extern "C" void kernel_launch(void* const* d_in, const int* in_sizes, int n_in,
                              void* d_out, int out_size, void* d_ws, size_t ws_size,
                              hipStream_t stream){
  (void)in_sizes; (void)n_in; (void)out_size;
  const float* xyz    = (const float*)d_in[0];
  const float* points = (const float*)d_in[1];
  const float* w0 = (const float*)d_in[2];
  const float* b0 = (const float*)d_in[3];
  const float* g0 = (const float*)d_in[4];
  const float* be0= (const float*)d_in[5];
  const float* w1 = (const float*)d_in[6];
  const float* b1 = (const float*)d_in[7];
  const float* g1 = (const float*)d_in[8];
  const float* be1= (const float*)d_in[9];
  const float* w2 = (const float*)d_in[10];
  const float* b2 = (const float*)d_in[11];
  const float* g2 = (const float*)d_in[12];
  const float* be2= (const float*)d_in[13];

  float* out_newxyz = (float*)d_out;
  float* out_newpts = out_newxyz + (size_t)NB*NS*3;

  char* ws = (char*)d_ws;
  int*   idx = (int*)ws;                              // 1 MiB (ord overlays first 512KB)
  float* ac  = (float*)(ws + (1u<<20));               // 512 floats
  float* pS  = (float*)(ws + (1u<<20) + 4096);        // 2048*128 f
  float* pQ  = pS + (size_t)NBLK*128;                 // 2048*128 f
  float* mxp = pQ + (size_t)NBLK*128;                 // 8192*128 f
  float* mnp = mxp + (size_t)NG*128;                  // 8192*128 f
  float* pP  = mnp + (size_t)NG*128;                  // 16*2*128 f = 16KB
  const size_t need = (1u<<20) + 4096 + (size_t)2*NBLK*128*4 + (size_t)2*NG*128*4
                    + (size_t)SBLK*2*128*4;
  if (ws_size < need) return;  // ~11.5 MiB required

  int* ord = idx;   // reuse: written by k_morton, read by k_fps, then overwritten by k_ball

  k_morton<<<NB, 1024, 0, stream>>>(xyz, ord);
  k_fps  <<<NB, 1024, 0, stream>>>(xyz, ord, out_newxyz);
  k_ball <<<NG/4, 256, 0, stream>>>(xyz, out_newxyz, idx);

  k_pass<0><<<NBLK,256,0,stream>>>(xyz,points,out_newxyz,idx,w0,b0,w1,b1,w2,b2,ac,pS,pQ,mxp,mnp);
  k_stats1<<<SBLK,1024,0,stream>>>(pS,pQ,pP,64);
  k_stats2<<<1,128,0,stream>>>(pP,g0,be0, ac+0,   ac+64,  64);
  k_pass<1><<<NBLK,256,0,stream>>>(xyz,points,out_newxyz,idx,w0,b0,w1,b1,w2,b2,ac,pS,pQ,mxp,mnp);
  k_stats1<<<SBLK,1024,0,stream>>>(pS,pQ,pP,64);
  k_stats2<<<1,128,0,stream>>>(pP,g1,be1, ac+128, ac+192, 64);
  k_pass<2><<<NBLK,256,0,stream>>>(xyz,points,out_newxyz,idx,w0,b0,w1,b1,w2,b2,ac,pS,pQ,mxp,mnp);
  k_stats1<<<SBLK,1024,0,stream>>>(pS,pQ,pP,128);
  k_stats2<<<1,128,0,stream>>>(pP,g2,be2, ac+256, ac+384, 128);
  k_final<<<(NG*128)/256,256,0,stream>>>(mxp,mnp,ac+256,ac+384,out_newpts);
}

// Round 19
// 1010.650 us; speedup vs baseline: 1.1641x; 1.0189x over previous
//
#include <hip/hip_runtime.h>
#include <hip/hip_bf16.h>
#include <cstdint>
#include <cstddef>

#define NB 16
#define NN 8192
#define NS 512
#define NK 32
#define NG (NB*NS)          // 8192 groups
#define GPB 4               // groups per pass-block
#define NBLK (NG/GPB)       // 2048
#define NPOSI 262144        // NG*NK positions
#define SBLK 16             // stats stage-1 blocks

// float64 squared distance, numpy order ((dx*dx + dy*dy) + dz*dz), no contraction.
__device__ __forceinline__ double sq3d(double dx, double dy, double dz){
#pragma clang fp contract(off)
  const double a = dx*dx;
  const double b = dy*dy;
  const double c = dz*dz;
  return (a + b) + c;
}

// one DPP-max step on a u32 (nonneg-float bitpattern: u32 order == float order)
template<int CTRL>
__device__ __forceinline__ unsigned dpp_umax_step(unsigned v){
  const unsigned o = (unsigned)__builtin_amdgcn_update_dpp(0, (int)v, CTRL, 0xf, 0xf, false);
  return v > o ? v : o;
}
// full-wave (64-lane) max; result valid in lane 63
__device__ __forceinline__ unsigned wave_umax63(unsigned v){
  v = dpp_umax_step<0xB1>(v);    // quad_perm xor1
  v = dpp_umax_step<0x4E>(v);    // quad_perm xor2
  v = dpp_umax_step<0x141>(v);   // row_half_mirror
  v = dpp_umax_step<0x140>(v);   // row_mirror
  v = dpp_umax_step<0x142>(v);   // row_bcast15
  v = dpp_umax_step<0x143>(v);   // row_bcast31 -> lane63 complete
  return v;
}
// max within each 16-lane group, result in ALL lanes of the group
__device__ __forceinline__ unsigned grp16_umax(unsigned v){
  v = dpp_umax_step<0xB1>(v);
  v = dpp_umax_step<0x4E>(v);
  v = dpp_umax_step<0x141>(v);
  v = dpp_umax_step<0x140>(v);
  return v;
}

// spread 4 bits to positions 0,3,6,9
__device__ __forceinline__ unsigned mort4(unsigned v){
  return (v & 1u) | ((v & 2u) << 2) | ((v & 4u) << 4) | ((v & 8u) << 6);
}

// bf16 pack/unpack (RNE)
__device__ __forceinline__ unsigned bf2pk(float lo, float hi){
  unsigned a=__float_as_uint(lo), b=__float_as_uint(hi);
  a = (a + 0x7fffu + ((a>>16)&1u)) >> 16;
  b = (b + 0x7fffu + ((b>>16)&1u)) >> 16;
  return (b<<16) | a;
}
__device__ __forceinline__ float bflo(unsigned u){ return __uint_as_float(u<<16); }
__device__ __forceinline__ float bfhi(unsigned u){ return __uint_as_float(u & 0xffff0000u); }

// ---------------- one-time Morton bucketing: ord[b][pos] = original index ----------------
__global__ __launch_bounds__(1024) void k_morton(const float* __restrict__ xyz,
                                                 int* __restrict__ ord){
  const int b = blockIdx.x;
  const int t = threadIdx.x;
  const float* __restrict__ X = xyz + (size_t)b*NN*3;
  __shared__ unsigned sHist[4096];
  __shared__ unsigned sWT[16];
  for (int k=t; k<4096; k+=1024) sHist[k] = 0u;
  __syncthreads();
  unsigned code[8];
#pragma unroll
  for (int j=0;j<8;++j){
    const int p = t + 1024*j;
    const float x=X[p*3+0], y=X[p*3+1], z=X[p*3+2];
    const unsigned ix=(unsigned)min(15,max(0,(int)(x*16.f)));
    const unsigned iy=(unsigned)min(15,max(0,(int)(y*16.f)));
    const unsigned iz=(unsigned)min(15,max(0,(int)(z*16.f)));
    code[j] = mort4(ix) | (mort4(iy)<<1) | (mort4(iz)<<2);
    atomicAdd(&sHist[code[j]], 1u);
  }
  __syncthreads();
  // exclusive scan over 4096 bins (thread owns 4 bins)
  {
    const uint4 h = ((const uint4*)sHist)[t];
    const unsigned l1=h.x, l2=h.x+h.y, l3=h.x+h.y+h.z, tot=l3+h.w;
    unsigned inc = tot;
    const int lane = t & 63;
#pragma unroll
    for (int d2=1; d2<64; d2<<=1){
      const unsigned v = __shfl_up(inc, d2);
      if (lane >= d2) inc += v;
    }
    const unsigned wexc = inc - tot;
    if (lane == 63) sWT[t>>6] = inc;
    __syncthreads();
    if (t == 0){
      unsigned run = 0;
#pragma unroll
      for (int k=0;k<16;++k){ const unsigned v=sWT[k]; sWT[k]=run; run+=v; }
    }
    __syncthreads();
    const unsigned base = sWT[t>>6] + wexc;
    uint4 o; o.x=base; o.y=base+l1; o.z=base+l2; o.w=base+l3;
    ((uint4*)sHist)[t] = o;
  }
  __syncthreads();
#pragma unroll
  for (int j=0;j<8;++j){
    const unsigned pos = atomicAdd(&sHist[code[j]], 1u);
    ord[(size_t)b*NN + pos] = t + 1024*j;
  }
}

// ---------------- FPS: flat 1-hop handshake (1 read/lane/poll), exact argmax ----------------
// (Exact R15/R17 structure — measured best 754 us. FROZEN.)
__global__ __launch_bounds__(1024) void k_fps(const float* __restrict__ xyz,
                                              const int* __restrict__ ord,
                                              float* __restrict__ newxyz){
  const int b = blockIdx.x;
  const int t = threadIdx.x;
  const float* __restrict__ X = xyz + (size_t)b*NN*3;

  __shared__ float4 sP[NN];                      // 128 KB, original index order
  __shared__ unsigned long long sW0[2][16];      // packed {wf:32 | (i+1)<<13 | idx:13}
  __shared__ unsigned long long sWv64[2][16];    // exact f64 bits (side slot)

  int oidx[8];
#pragma unroll
  for (int j=0;j<8;++j){
    const int p = t + 1024*j;
    sP[p] = make_float4(X[p*3+0], X[p*3+1], X[p*3+2], 0.f);
    oidx[j] = ord[(size_t)b*NN + 8*t + j];
  }
  if (t < 16){ sW0[0][t]=0ull; sW0[1][t]=0ull; }
  __syncthreads();     // only barrier

  float px[8], py[8], pz[8], thr[8];
  double dd[8];
#pragma unroll
  for (int j=0;j<8;++j){
    const float4 q = sP[oidx[j]];
    px[j]=q.x; py[j]=q.y; pz[j]=q.z;
    dd[j]=1e10;
    thr[j]=fmaf(1e10f, 0x1p-19f, 1e10f);
  }
  // bounding sphere of owned (Morton-adjacent) points, conservative margins
  float ctx=0.f, cty=0.f, ctz=0.f;
#pragma unroll
  for (int j=0;j<8;++j){ ctx+=px[j]; cty+=py[j]; ctz+=pz[j]; }
  ctx*=0.125f; cty*=0.125f; ctz*=0.125f;
  float r2m = 0.f;
#pragma unroll
  for (int j=0;j<8;++j){
    const float ax=px[j]-ctx, ay=py[j]-cty, az=pz[j]-ctz;
    r2m = fmaxf(r2m, fmaf(az,az,fmaf(ay,ay,ax*ax)));
  }
  const float rT = sqrtf(r2m)*(1.0f+0x1p-18f) + 0x1p-20f;

  double tmax = 1e10;
  float  tmax32 = 1e10f;
  int tio = oidx[0], ts = 0;
#pragma unroll
  for (int j=1;j<8;++j) if (oidx[j] < tio){ tio = oidx[j]; ts = j; }
  float skipgate = tmax32*(1.0f+0x1p-14f);

  int f = 0;
  const int lane = t & 63, wid = t >> 6;

  for (int i=0;i<NS-1;++i){
    const int par = i & 1;
    const float4 cf = sP[f];                 // uniform LDS broadcast
    const float cx=cf.x, cy=cf.y, cz=cf.z;
    if (t == 0){                             // fire-and-forget centroid store
      float* o = newxyz + ((size_t)b*NS + i)*3;
      o[0]=cx; o[1]=cy; o[2]=cz;
    }

    // ---- thread-level conservative skip ----
    const float bx=cx-ctx, by=cy-cty, bz=cz-ctz;
    const float ddc = fmaf(bz,bz,fmaf(by,by,bx*bx));
    const float dcc = sqrtf(ddc);
    float s = dcc - rT; s = s - dcc*0x1p-16f;
    const bool engage = !(s > 0.f && s*s >= skipgate);

    if (engage){
      float e[8]; float mmin = 1e30f;
#pragma unroll
      for (int j=0;j<8;++j){
        const float ax=px[j]-cx, ay=py[j]-cy, az=pz[j]-cz;
        const float d32 = fmaf(az, az, fmaf(ay, ay, ax*ax));
        e[j] = d32 - thr[j];
        mmin = fminf(mmin, e[j]);
      }
      if (__builtin_expect(mmin <= 0.f, 0)){
        const double cxd=(double)cx, cyd=(double)cy, czd=(double)cz;
        bool needscan = false;
#pragma unroll
        for (int j=0;j<8;++j){
          if (e[j] <= 0.f){
            const double d64 = sq3d((double)px[j]-cxd, (double)py[j]-cyd, (double)pz[j]-czd);
            const double nd = fmin(dd[j], d64);
            needscan |= (j == ts) | (nd == tmax);
            dd[j] = nd;
            const float nd32 = (float)nd;
            thr[j] = fmaf(nd32, 0x1p-19f, nd32);
          }
        }
        if (needscan){
          double tm = dd[0]; int io = oidx[0]; int s0 = 0;
#pragma unroll
          for (int j=1;j<8;++j)
            if (dd[j] > tm || (dd[j] == tm && oidx[j] < io)){ tm=dd[j]; io=oidx[j]; s0=j; }
          tmax=tm; tio=io; ts=s0; tmax32=(float)tm;
          skipgate = tmax32*(1.0f+0x1p-14f);
        }
      }
    }

    // ---- in-wave exact winner (f32 DPP + candidate resolve), single writer ----
    const unsigned myb = __float_as_uint(tmax32);
    const unsigned wm = (unsigned)__builtin_amdgcn_readlane((int)wave_umax63(myb), 63);
    const unsigned long long mask = __ballot(myb == wm);
    int writer;
    if (__builtin_expect(__popcll(mask) == 1, 1)){
      writer = (int)__builtin_ctzll(mask);
    } else {
      double bestv = -1.0; int bestid = 0x7fffffff;
      unsigned long long mm = mask;
      while (mm){
        const int l = (int)__builtin_ctzll(mm);
        const double v = __shfl(tmax, l);
        const int   id = __shfl(tio, l);
        if (v > bestv || (v == bestv && id < bestid)){ bestv=v; bestid=id; }
        mm &= mm - 1;
      }
      writer = (int)__builtin_ctzll(__ballot(tmax == bestv && tio == bestid));
    }
    if (lane == writer){
      sWv64[par][wid] = (unsigned long long)__double_as_longlong(tmax);
      const unsigned long long pk = ((unsigned long long)wm << 32)
                                  | ((unsigned long long)(unsigned)(i+1) << 13)
                                  | (unsigned long long)(unsigned)tio;
      __hip_atomic_store(&sW0[par][wid], pk,
                         __ATOMIC_RELEASE, __HIP_MEMORY_SCOPE_WORKGROUP);
    }

    // ---- flat block reduce: ONE b64 read per lane per poll round ----
    const unsigned want = (unsigned)(i+1);
    unsigned long long w;
    do {
      w = __hip_atomic_load(&sW0[par][lane & 15],
                            __ATOMIC_RELAXED, __HIP_MEMORY_SCOPE_WORKGROUP);
    } while (__ballot((((unsigned)w >> 13) & 1023u) == want) != ~0ull);
    __builtin_amdgcn_fence(__ATOMIC_ACQUIRE, "workgroup");

    const unsigned wf   = (unsigned)(w >> 32);
    const unsigned idxw = (unsigned)w & 8191u;
    const unsigned m32  = grp16_umax(wf);          // block max, all lanes
    const unsigned long long cm = __ballot(wf == m32);
    if (__builtin_expect(__popcll(cm) == 4, 1)){   // unique slot (x4 replicas)
      f = __shfl((int)idxw, (int)__builtin_ctzll(cm));
    } else {
      // rare: exact f64 resolve among f32-bit-tied slots (max value, min index)
      unsigned long long mm = cm & 0xFFFFull;      // one replica set
      double bv = -1.0; int bid = 0x7fffffff;
      while (mm){
        const int l = (int)__builtin_ctzll(mm);
        const double v = __longlong_as_double((long long)sWv64[par][l]); // uniform bcast
        const int   id = __shfl((int)idxw, l);
        if (v > bv || (v == bv && id < bid)){ bv = v; bid = id; }
        mm &= mm - 1;
      }
      f = bid;
    }
  }
  // last centroid
  if (t == 0){
    const float4 cf = sP[f];
    float* o = newxyz + ((size_t)b*NS + (NS-1))*3;
    o[0]=cf.x; o[1]=cf.y; o[2]=cf.z;
  }
}

// ---------------- Ball query: one wave per centroid, f32 screen + f64 band ----------------
__global__ __launch_bounds__(256) void k_ball(const float* __restrict__ xyz,
                                              const float* __restrict__ newxyz,
                                              int* __restrict__ idx){
  const int w = (blockIdx.x << 2) + (threadIdx.x >> 6);  // group id = b*NS+s
  const int lane = threadIdx.x & 63;
  const int b = w >> 9;
  const float* __restrict__ C = newxyz + (size_t)w*3;
  const float cxf=C[0], cyf=C[1], czf=C[2];
  const double cx=(double)cxf, cy=(double)cyf, cz=(double)czf;
  const float* __restrict__ X = xyz + (size_t)b*NN*3;
  int* __restrict__ out = idx + (size_t)w*NK;
  const double R2 = 0.2*0.2;                   // f64: 0.04000000000000000083...
  const float r2lo = 0.04f*(1.0f - 0x1p-16f);  // certain-in  below
  const float r2hi = 0.04f*(1.0f + 0x1p-16f);  // certain-out above
  int count = 0, first = 0;
  for (int base=0; base<NN && count<NK; base+=64){
    const int p = base + lane;
    const float ax=X[p*3+0]-cxf, ay=X[p*3+1]-cyf, az=X[p*3+2]-czf;
    const float d32 = fmaf(az, az, fmaf(ay, ay, ax*ax));
    bool q;
    if (d32 <= r2lo)      q = true;
    else if (d32 > r2hi)  q = false;
    else {                                     // rare band: exact f64 decision
      const double d = sq3d((double)X[p*3+0]-cx, (double)X[p*3+1]-cy, (double)X[p*3+2]-cz);
      q = !(d > R2);
    }
    const unsigned long long m = __ballot(q);
    if (q){
      const int pos = count + __popcll(m & ((1ull<<lane)-1ull));
      if (pos < NK) out[pos] = p;
    }
    if (count == 0 && m) first = base + __builtin_ctzll(m);
    count += __popcll(m);
  }
  if (lane >= count && lane < NK) out[lane] = first;   // pad with first index
}

// ---------------- per-block stats (+optional group min/max) reduction ----------------
__device__ __forceinline__ void stats_reduce(
    float v[4][8], float* __restrict__ sRed, int t, int tp, int tc, int blk,
    int chtot, int choff, bool domm,
    float* __restrict__ pS, float* __restrict__ pQ,
    float* __restrict__ mxp, float* __restrict__ mnp)
{
  __syncthreads();   // sRed overlays sX0/sW0/sV — ensure all prior reads done
  float S=0.f, Q=0.f;
  for (int m=0;m<4;++m){
#pragma unroll
    for (int i=0;i<8;++i) sRed[tp*68 + tc*8 + i] = v[m][i];
    __syncthreads();
    if (t < 64){
      float mxv = -3.402823466e38f, mnv = 3.402823466e38f;
#pragma unroll
      for (int j=0;j<32;++j){
        const float x = sRed[j*68 + t];
        S += x; Q += x*x;
        mxv = fmaxf(mxv,x); mnv = fminf(mnv,x);
      }
      if (domm){
        const int gg = blk*GPB + m;
        mxp[(size_t)gg*128 + choff + t] = mxv;
        mnp[(size_t)gg*128 + choff + t] = mnv;
      }
    }
    __syncthreads();
  }
  if (t < 64){
    pS[(size_t)blk*chtot + choff + t] = S;
    pQ[(size_t)blk*chtot + choff + t] = Q;
  }
}

// 64-deep inner product accumulate: v[m][i] += sX[pos_m][k]*sW[ch_i][k]
__device__ __forceinline__ void mm64(const float* __restrict__ sXl,
                                     const float* __restrict__ sWl,
                                     int tp, int tc, float v[4][8]){
#pragma unroll 4
  for (int k=0;k<64;++k){
    float xv[4], wv[8];
#pragma unroll
    for (int m=0;m<4;++m) xv[m] = sXl[(tp+32*m)*65 + k];
#pragma unroll
    for (int i=0;i<8;++i) wv[i] = sWl[(tc*8+i)*65 + k];
#pragma unroll
    for (int m=0;m<4;++m)
#pragma unroll
      for (int i=0;i<8;++i) v[m][i] += xv[m]*wv[i];
  }
}

// ---------------- MLP pass: recompute chain to layer DEPTH, emit stats ----------------
template<int DEPTH>
__global__ __launch_bounds__(256) void k_pass(
    const float* __restrict__ xyz, const float* __restrict__ points,
    const float* __restrict__ newxyz, const int* __restrict__ idx,
    const float* __restrict__ w0, const float* __restrict__ b0,
    const float* __restrict__ w1, const float* __restrict__ b1,
    const float* __restrict__ w2, const float* __restrict__ b2,
    const float* __restrict__ ac,
    float* __restrict__ pS, float* __restrict__ pQ,
    float* __restrict__ mxp, float* __restrict__ mnp)
{
  __shared__ float smem[(DEPTH>=1) ? 14784 : 2304];
  float* sX0 = smem;
  float* sW0 = smem + 1024;
  float* sV  = smem + 1600;
  float* sRed= smem;            // overlay
  float* sB2 = smem + 2176;
  float* sW1 = smem + 2304;
  float* sX  = smem + 6464;

  const int t = threadIdx.x;
  const int blk = blockIdx.x;
  const int tc = t & 7, tp = t >> 3;

  // stage weights / params
  for (int i=t;i<384;i+=256) sW0[(i/6)*9 + (i%6)] = w0[i];
  if (t < 64) sV[t] = b0[t];
  if constexpr (DEPTH >= 1){
    if (t < 64){ sV[64+t]=ac[t]; sV[128+t]=ac[64+t]; sV[192+t]=b1[t]; }
    for (int i=t;i<4096;i+=256) sW1[(i>>6)*65 + (i&63)] = w1[i];
  }
  if constexpr (DEPTH == 2){
    if (t < 64){ sV[256+t]=ac[128+t]; sV[320+t]=ac[192+t]; }
    if (t < 128) sB2[t] = b2[t];
  }

  // gather -> x0 (6 ch): [gxyz - centroid, gpts]
  {
    const int pos = t & 127;
    const int gg = blk*GPB + (pos >> 5);
    const int b  = gg >> 9;
    const int id = idx[gg*NK + (pos & 31)];
    if (t < 128){
      const float* __restrict__ P = xyz + ((size_t)b*NN + id)*3;
      const float* __restrict__ C = newxyz + (size_t)gg*3;
      sX0[pos*8+0] = P[0]-C[0];
      sX0[pos*8+1] = P[1]-C[1];
      sX0[pos*8+2] = P[2]-C[2];
    } else {
      const float* __restrict__ P = points + ((size_t)b*NN + id)*3;
      sX0[pos*8+3] = P[0];
      sX0[pos*8+4] = P[1];
      sX0[pos*8+5] = P[2];
    }
  }
  __syncthreads();

  // y0 = W0 x0 + b0   (thread: 4 positions x 8 channels)
  float v[4][8];
#pragma unroll
  for (int m=0;m<4;++m){
    const int pos = tp + 32*m;
    float xr[6];
#pragma unroll
    for (int c=0;c<6;++c) xr[c] = sX0[pos*8+c];
#pragma unroll
    for (int i=0;i<8;++i){
      const int ch = tc*8+i;
      float acc = sV[ch];
#pragma unroll
      for (int c=0;c<6;++c) acc += sW0[ch*9+c]*xr[c];
      v[m][i] = acc;
    }
  }

  if constexpr (DEPTH == 0){
    stats_reduce(v, sRed, t, tp, tc, blk, 64, 0, false, pS, pQ, mxp, mnp);
    return;
  } else {
    // x1 = relu(a0*y0 + c0)
#pragma unroll
    for (int m=0;m<4;++m){
      const int pos = tp + 32*m;
#pragma unroll
      for (int i=0;i<8;++i){
        const int ch = tc*8+i;
        sX[pos*65+ch] = fmaxf(sV[64+ch]*v[m][i] + sV[128+ch], 0.f);
      }
    }
    __syncthreads();
    // y1 = W1 x1 + b1
#pragma unroll
    for (int m=0;m<4;++m)
#pragma unroll
      for (int i=0;i<8;++i) v[m][i] = sV[192 + tc*8 + i];
    mm64(sX, sW1, tp, tc, v);

    if constexpr (DEPTH == 1){
      stats_reduce(v, sRed, t, tp, tc, blk, 64, 0, false, pS, pQ, mxp, mnp);
      return;
    } else {
      __syncthreads();
      // x2 = relu(a1*y1 + c1), overwrite sX
#pragma unroll
      for (int m=0;m<4;++m){
        const int pos = tp + 32*m;
#pragma unroll
        for (int i=0;i<8;++i){
          const int ch = tc*8+i;
          sX[pos*65+ch] = fmaxf(sV[256+ch]*v[m][i] + sV[320+ch], 0.f);
        }
      }
      __syncthreads();
      // y2 = W2 x2 + b2 in two 64-channel chunks (W2 chunk reuses sW1 space)
      for (int o=0;o<2;++o){
        for (int i=t;i<4096;i+=256) sW1[(i>>6)*65 + (i&63)] = w2[o*4096 + i];
        __syncthreads();
#pragma unroll
        for (int m=0;m<4;++m)
#pragma unroll
          for (int i=0;i<8;++i) v[m][i] = sB2[o*64 + tc*8 + i];
        mm64(sX, sW1, tp, tc, v);
        stats_reduce(v, sRed, t, tp, tc, blk, 128, o*64, true, pS, pQ, mxp, mnp);
      }
      return;
    }
  }
}

// ---------------- pass1 + store y1 (bf16) for the cached pass2 path ----------------
__global__ __launch_bounds__(256) void k_pass1s(
    const float* __restrict__ xyz, const float* __restrict__ points,
    const float* __restrict__ newxyz, const int* __restrict__ idx,
    const float* __restrict__ w0, const float* __restrict__ b0,
    const float* __restrict__ w1, const float* __restrict__ b1,
    const float* __restrict__ ac, unsigned* __restrict__ y1c,
    float* __restrict__ pS, float* __restrict__ pQ,
    float* __restrict__ mxp, float* __restrict__ mnp)
{
  __shared__ float smem[14784];
  float* sX0 = smem;
  float* sW0 = smem + 1024;
  float* sV  = smem + 1600;
  float* sRed= smem;
  float* sW1 = smem + 2304;
  float* sX  = smem + 6464;

  const int t = threadIdx.x;
  const int blk = blockIdx.x;
  const int tc = t & 7, tp = t >> 3;

  for (int i=t;i<384;i+=256) sW0[(i/6)*9 + (i%6)] = w0[i];
  if (t < 64){ sV[t]=b0[t]; sV[64+t]=ac[t]; sV[128+t]=ac[64+t]; sV[192+t]=b1[t]; }
  for (int i=t;i<4096;i+=256) sW1[(i>>6)*65 + (i&63)] = w1[i];

  {
    const int pos = t & 127;
    const int gg = blk*GPB + (pos >> 5);
    const int b  = gg >> 9;
    const int id = idx[gg*NK + (pos & 31)];
    if (t < 128){
      const float* __restrict__ P = xyz + ((size_t)b*NN + id)*3;
      const float* __restrict__ C = newxyz + (size_t)gg*3;
      sX0[pos*8+0] = P[0]-C[0];
      sX0[pos*8+1] = P[1]-C[1];
      sX0[pos*8+2] = P[2]-C[2];
    } else {
      const float* __restrict__ P = points + ((size_t)b*NN + id)*3;
      sX0[pos*8+3] = P[0];
      sX0[pos*8+4] = P[1];
      sX0[pos*8+5] = P[2];
    }
  }
  __syncthreads();

  float v[4][8];
#pragma unroll
  for (int m=0;m<4;++m){
    const int pos = tp + 32*m;
    float xr[6];
#pragma unroll
    for (int c=0;c<6;++c) xr[c] = sX0[pos*8+c];
#pragma unroll
    for (int i=0;i<8;++i){
      const int ch = tc*8+i;
      float acc = sV[ch];
#pragma unroll
      for (int c=0;c<6;++c) acc += sW0[ch*9+c]*xr[c];
      v[m][i] = acc;
    }
  }
  // x1 = relu(a0*y0 + c0)
#pragma unroll
  for (int m=0;m<4;++m){
    const int pos = tp + 32*m;
#pragma unroll
    for (int i=0;i<8;++i){
      const int ch = tc*8+i;
      sX[pos*65+ch] = fmaxf(sV[64+ch]*v[m][i] + sV[128+ch], 0.f);
    }
  }
  __syncthreads();
  // y1 = W1 x1 + b1
#pragma unroll
  for (int m=0;m<4;++m)
#pragma unroll
    for (int i=0;i<8;++i) v[m][i] = sV[192 + tc*8 + i];
  mm64(sX, sW1, tp, tc, v);

  // store y1 as bf16: per pos, 64 ch = 8 uint4 slots; this thread owns slot tc
#pragma unroll
  for (int m=0;m<4;++m){
    const int pos = tp + 32*m;
    uint4 pk;
    pk.x = bf2pk(v[m][0], v[m][1]);
    pk.y = bf2pk(v[m][2], v[m][3]);
    pk.z = bf2pk(v[m][4], v[m][5]);
    pk.w = bf2pk(v[m][6], v[m][7]);
    ((uint4*)y1c)[((size_t)blk*128 + pos)*8 + tc] = pk;
  }

  stats_reduce(v, sRed, t, tp, tc, blk, 64, 0, false, pS, pQ, mxp, mnp);
}

// ---------------- pass2 from cached y1 (bf16): x2=relu(a1*y1+c1); layer2 ----------------
__global__ __launch_bounds__(256) void k_pass2l(
    const unsigned* __restrict__ y1c,
    const float* __restrict__ w2, const float* __restrict__ b2,
    const float* __restrict__ ac,
    float* __restrict__ pS, float* __restrict__ pQ,
    float* __restrict__ mxp, float* __restrict__ mnp)
{
  __shared__ float smem[14784];
  float* sV  = smem + 1600;
  float* sRed= smem;
  float* sB2 = smem + 2176;
  float* sW1 = smem + 2304;
  float* sX  = smem + 6464;

  const int t = threadIdx.x;
  const int blk = blockIdx.x;
  const int tc = t & 7, tp = t >> 3;

  if (t < 64){ sV[t]=ac[128+t]; sV[64+t]=ac[192+t]; }   // a1, c1
  if (t < 128) sB2[t] = b2[t];

  // load y1 (bf16) for this block's 128 positions
  float v[4][8];
#pragma unroll
  for (int m=0;m<4;++m){
    const int pos = tp + 32*m;
    const uint4 pk = ((const uint4*)y1c)[((size_t)blk*128 + pos)*8 + tc];
    v[m][0]=bflo(pk.x); v[m][1]=bfhi(pk.x);
    v[m][2]=bflo(pk.y); v[m][3]=bfhi(pk.y);
    v[m][4]=bflo(pk.z); v[m][5]=bfhi(pk.z);
    v[m][6]=bflo(pk.w); v[m][7]=bfhi(pk.w);
  }
  __syncthreads();   // sV/sB2 ready

  // x2 = relu(a1*y1 + c1)
#pragma unroll
  for (int m=0;m<4;++m){
    const int pos = tp + 32*m;
#pragma unroll
    for (int i=0;i<8;++i){
      const int ch = tc*8+i;
      sX[pos*65+ch] = fmaxf(sV[ch]*v[m][i] + sV[64+ch], 0.f);
    }
  }
  __syncthreads();

  for (int o=0;o<2;++o){
    for (int i2=t;i2<4096;i2+=256) sW1[(i2>>6)*65 + (i2&63)] = w2[o*4096 + i2];
    __syncthreads();
#pragma unroll
    for (int m=0;m<4;++m)
#pragma unroll
      for (int i=0;i<8;++i) v[m][i] = sB2[o*64 + tc*8 + i];
    mm64(sX, sW1, tp, tc, v);
    stats_reduce(v, sRed, t, tp, tc, blk, 128, o*64, true, pS, pQ, mxp, mnp);
  }
}

// ---------------- stats stage 1: 16 blocks, each sums NBLK/16 partial rows ----------------
__global__ __launch_bounds__(1024) void k_stats1(const float* __restrict__ pS,
                                                 const float* __restrict__ pQ,
                                                 float* __restrict__ pP, int CH){
  __shared__ float sS[1024], sQ[1024];
  const int t = threadIdx.x, blk = blockIdx.x;
  const int ch = t & (CH-1);
  const int seg = t / CH;
  const int SEG = 1024 / CH;                 // 16 (CH=64) or 8 (CH=128)
  const int rows = (NBLK/SBLK) / SEG;        // 8 or 16
  const int j0 = blk*(NBLK/SBLK) + seg*rows;
  float S=0.f, Q=0.f;
#pragma unroll 4
  for (int r=0;r<rows;++r){
    const size_t o = (size_t)(j0+r)*CH + ch;
    S += pS[o]; Q += pQ[o];
  }
  sS[t]=S; sQ[t]=Q;
  __syncthreads();
  if (t < CH){
    float aS=0.f, aQ=0.f;
    for (int s2=0;s2<SEG;++s2){ aS += sS[s2*CH+ch]; aQ += sQ[s2*CH+ch]; }
    pP[(size_t)blk*2*CH + ch]      = aS;
    pP[(size_t)blk*2*CH + CH + ch] = aQ;
  }
}

// ---------------- stats stage 2: fold 16 partials, derive a,c ----------------
__global__ __launch_bounds__(128) void k_stats2(const float* __restrict__ pP,
                                                const float* __restrict__ g,
                                                const float* __restrict__ beta,
                                                float* __restrict__ a, float* __restrict__ c,
                                                int CH){
  const int ch = threadIdx.x;
  if (ch >= CH) return;
  float S=0.f, Q=0.f;
#pragma unroll
  for (int k=0;k<SBLK;++k){
    S += pP[(size_t)k*2*CH + ch];
    Q += pP[(size_t)k*2*CH + CH + ch];
  }
  const float mean = S * (1.f/(float)NPOSI);
  const float var  = fmaxf(Q * (1.f/(float)NPOSI) - mean*mean, 0.f);
  const float av = g[ch] * rsqrtf(var + 1e-5f);
  a[ch] = av;
  c[ch] = beta[ch] - mean*av;
}

// ---------------- final: BN+ReLU applied to pooled value ----------------
__global__ __launch_bounds__(256) void k_final(const float* __restrict__ mxp, const float* __restrict__ mnp,
                                               const float* __restrict__ a, const float* __restrict__ c,
                                               float* __restrict__ out){
  const int i = blockIdx.x*256 + threadIdx.x;
  const int ch = i & 127;
  const float av = a[ch], cv = c[ch];
  const float vv = (av >= 0.f) ? mxp[i] : mnp[i];   // relu∘affine is monotone
  out[i] = fmaxf(av*vv + cv, 0.f);
}

extern "C" void kernel_launch(void* const* d_in, const int* in_sizes, int n_in,
                              void* d_out, int out_size, void* d_ws, size_t ws_size,
                              hipStream_t stream){
  (void)in_sizes; (void)n_in; (void)out_size;
  const float* xyz    = (const float*)d_in[0];
  const float* points = (const float*)d_in[1];
  const float* w0 = (const float*)d_in[2];
  const float* b0 = (const float*)d_in[3];
  const float* g0 = (const float*)d_in[4];
  const float* be0= (const float*)d_in[5];
  const float* w1 = (const float*)d_in[6];
  const float* b1 = (const float*)d_in[7];
  const float* g1 = (const float*)d_in[8];
  const float* be1= (const float*)d_in[9];
  const float* w2 = (const float*)d_in[10];
  const float* b2 = (const float*)d_in[11];
  const float* g2 = (const float*)d_in[12];
  const float* be2= (const float*)d_in[13];

  float* out_newxyz = (float*)d_out;
  float* out_newpts = out_newxyz + (size_t)NB*NS*3;

  char* ws = (char*)d_ws;
  int*   idx = (int*)ws;                              // 1 MiB (ord overlays first 512KB)
  float* ac  = (float*)(ws + (1u<<20));               // 512 floats
  float* pS  = (float*)(ws + (1u<<20) + 4096);        // 2048*128 f
  float* pQ  = pS + (size_t)NBLK*128;                 // 2048*128 f
  float* mxp = pQ + (size_t)NBLK*128;                 // 8192*128 f
  float* mnp = mxp + (size_t)NG*128;                  // 8192*128 f
  float* pP  = mnp + (size_t)NG*128;                  // 16*2*128 f = 16KB
  unsigned* y1c = (unsigned*)(pP + (size_t)SBLK*2*128);  // 262144*64 bf16 = 33.5MB
  const size_t need_small = (1u<<20) + 4096 + (size_t)2*NBLK*128*4 + (size_t)2*NG*128*4
                          + (size_t)SBLK*2*128*4;
  const size_t need_big   = need_small + (size_t)NPOSI*64*2;
  if (ws_size < need_small) return;
  const bool big = (ws_size >= need_big);

  int* ord = idx;   // reuse: written by k_morton, read by k_fps, then overwritten by k_ball

  k_morton<<<NB, 1024, 0, stream>>>(xyz, ord);
  k_fps  <<<NB, 1024, 0, stream>>>(xyz, ord, out_newxyz);
  k_ball <<<NG/4, 256, 0, stream>>>(xyz, out_newxyz, idx);

  k_pass<0><<<NBLK,256,0,stream>>>(xyz,points,out_newxyz,idx,w0,b0,w1,b1,w2,b2,ac,pS,pQ,mxp,mnp);
  k_stats1<<<SBLK,1024,0,stream>>>(pS,pQ,pP,64);
  k_stats2<<<1,128,0,stream>>>(pP,g0,be0, ac+0,   ac+64,  64);
  if (big){
    k_pass1s<<<NBLK,256,0,stream>>>(xyz,points,out_newxyz,idx,w0,b0,w1,b1,ac,y1c,pS,pQ,mxp,mnp);
    k_stats1<<<SBLK,1024,0,stream>>>(pS,pQ,pP,64);
    k_stats2<<<1,128,0,stream>>>(pP,g1,be1, ac+128, ac+192, 64);
    k_pass2l<<<NBLK,256,0,stream>>>(y1c,w2,b2,ac,pS,pQ,mxp,mnp);
  } else {
    k_pass<1><<<NBLK,256,0,stream>>>(xyz,points,out_newxyz,idx,w0,b0,w1,b1,w2,b2,ac,pS,pQ,mxp,mnp);
    k_stats1<<<SBLK,1024,0,stream>>>(pS,pQ,pP,64);
    k_stats2<<<1,128,0,stream>>>(pP,g1,be1, ac+128, ac+192, 64);
    k_pass<2><<<NBLK,256,0,stream>>>(xyz,points,out_newxyz,idx,w0,b0,w1,b1,w2,b2,ac,pS,pQ,mxp,mnp);
  }
  k_stats1<<<SBLK,1024,0,stream>>>(pS,pQ,pP,128);
  k_stats2<<<1,128,0,stream>>>(pP,g2,be2, ac+256, ac+384, 128);
  k_final<<<(NG*128)/256,256,0,stream>>>(mxp,mnp,ac+256,ac+384,out_newpts);
}

// Round 20
// 1001.696 us; speedup vs baseline: 1.1745x; 1.0089x over previous
//
#include <hip/hip_runtime.h>
#include <hip/hip_bf16.h>
#include <cstdint>
#include <cstddef>

#define NB 16
#define NN 8192
#define NS 512
#define NK 32
#define NG (NB*NS)          // 8192 groups
#define GPB 4               // groups per pass-block
#define NBLK (NG/GPB)       // 2048
#define NPOSI 262144        // NG*NK positions
#define SBLK 16             // stats stage-1 blocks

// float64 squared distance, numpy order ((dx*dx + dy*dy) + dz*dz), no contraction.
__device__ __forceinline__ double sq3d(double dx, double dy, double dz){
#pragma clang fp contract(off)
  const double a = dx*dx;
  const double b = dy*dy;
  const double c = dz*dz;
  return (a + b) + c;
}

// one DPP-max step on a u32 (nonneg-float bitpattern: u32 order == float order)
template<int CTRL>
__device__ __forceinline__ unsigned dpp_umax_step(unsigned v){
  const unsigned o = (unsigned)__builtin_amdgcn_update_dpp(0, (int)v, CTRL, 0xf, 0xf, false);
  return v > o ? v : o;
}
// full-wave (64-lane) max; result valid in lane 63
__device__ __forceinline__ unsigned wave_umax63(unsigned v){
  v = dpp_umax_step<0xB1>(v);    // quad_perm xor1
  v = dpp_umax_step<0x4E>(v);    // quad_perm xor2
  v = dpp_umax_step<0x141>(v);   // row_half_mirror
  v = dpp_umax_step<0x140>(v);   // row_mirror
  v = dpp_umax_step<0x142>(v);   // row_bcast15
  v = dpp_umax_step<0x143>(v);   // row_bcast31 -> lane63 complete
  return v;
}
// max within each 16-lane group, result in ALL lanes of the group
__device__ __forceinline__ unsigned grp16_umax(unsigned v){
  v = dpp_umax_step<0xB1>(v);
  v = dpp_umax_step<0x4E>(v);
  v = dpp_umax_step<0x141>(v);
  v = dpp_umax_step<0x140>(v);
  return v;
}

// spread 4 bits to positions 0,3,6,9
__device__ __forceinline__ unsigned mort4(unsigned v){
  return (v & 1u) | ((v & 2u) << 2) | ((v & 4u) << 4) | ((v & 8u) << 6);
}

// bf16 pack/unpack (RNE)
__device__ __forceinline__ unsigned bf2pk(float lo, float hi){
  unsigned a=__float_as_uint(lo), b=__float_as_uint(hi);
  a = (a + 0x7fffu + ((a>>16)&1u)) >> 16;
  b = (b + 0x7fffu + ((b>>16)&1u)) >> 16;
  return (b<<16) | a;
}
__device__ __forceinline__ float bflo(unsigned u){ return __uint_as_float(u<<16); }
__device__ __forceinline__ float bfhi(unsigned u){ return __uint_as_float(u & 0xffff0000u); }

// ---------------- one-time Morton bucketing: ord[b][pos] = original index ----------------
__global__ __launch_bounds__(1024) void k_morton(const float* __restrict__ xyz,
                                                 int* __restrict__ ord){
  const int b = blockIdx.x;
  const int t = threadIdx.x;
  const float* __restrict__ X = xyz + (size_t)b*NN*3;
  __shared__ unsigned sHist[4096];
  __shared__ unsigned sWT[16];
  for (int k=t; k<4096; k+=1024) sHist[k] = 0u;
  __syncthreads();
  unsigned code[8];
#pragma unroll
  for (int j=0;j<8;++j){
    const int p = t + 1024*j;
    const float x=X[p*3+0], y=X[p*3+1], z=X[p*3+2];
    const unsigned ix=(unsigned)min(15,max(0,(int)(x*16.f)));
    const unsigned iy=(unsigned)min(15,max(0,(int)(y*16.f)));
    const unsigned iz=(unsigned)min(15,max(0,(int)(z*16.f)));
    code[j] = mort4(ix) | (mort4(iy)<<1) | (mort4(iz)<<2);
    atomicAdd(&sHist[code[j]], 1u);
  }
  __syncthreads();
  // exclusive scan over 4096 bins (thread owns 4 bins)
  {
    const uint4 h = ((const uint4*)sHist)[t];
    const unsigned l1=h.x, l2=h.x+h.y, l3=h.x+h.y+h.z, tot=l3+h.w;
    unsigned inc = tot;
    const int lane = t & 63;
#pragma unroll
    for (int d2=1; d2<64; d2<<=1){
      const unsigned v = __shfl_up(inc, d2);
      if (lane >= d2) inc += v;
    }
    const unsigned wexc = inc - tot;
    if (lane == 63) sWT[t>>6] = inc;
    __syncthreads();
    if (t == 0){
      unsigned run = 0;
#pragma unroll
      for (int k=0;k<16;++k){ const unsigned v=sWT[k]; sWT[k]=run; run+=v; }
    }
    __syncthreads();
    const unsigned base = sWT[t>>6] + wexc;
    uint4 o; o.x=base; o.y=base+l1; o.z=base+l2; o.w=base+l3;
    ((uint4*)sHist)[t] = o;
  }
  __syncthreads();
#pragma unroll
  for (int j=0;j<8;++j){
    const unsigned pos = atomicAdd(&sHist[code[j]], 1u);
    ord[(size_t)b*NN + pos] = t + 1024*j;
  }
}

// ---------------- FPS: flat 1-hop handshake + cached publish + setprio ----------------
// Exactness invariants (numpy-f64-bit-exact), proven earlier rounds:
//  * dd[j] exact f64 min sq-dist (numpy order); screen thr=dd32*(1+2^-19) conservative;
//    Morton thread-skip margins conservative (R9/R12).
//  * wave winner: f32 DPP max -> ballot -> exact (f64,min-orig-idx) writer (R10);
//    CACHED when no lane updated this iteration (bit-identical by invariance, R16).
//  * block winner: lanes poll packed {wf32,tag,idx} (slot=lane&15, x4 replicated);
//    grp16 DPP f32 max = candidate superset (RN monotone); unique slot (popc==4) ->
//    readlane idx; ties -> exact f64 side-slot resolve (max val, min orig idx).
// Sync: release publish; readers 1-read/lane poll + acquire fence. Parity dbuf,
// max skew 1 iter. setprio(1) during compute/publish, setprio(0) during poll so
// spinning waves yield SIMD issue slots to the straggler wave (phase-split case).
__global__ __launch_bounds__(1024) void k_fps(const float* __restrict__ xyz,
                                              const int* __restrict__ ord,
                                              float* __restrict__ newxyz){
  const int b = blockIdx.x;
  const int t = threadIdx.x;
  const float* __restrict__ X = xyz + (size_t)b*NN*3;

  __shared__ float4 sP[NN];                      // 128 KB, original index order
  __shared__ unsigned long long sW0[2][16];      // packed {wf:32 | (i+1)<<13 | idx:13}
  __shared__ unsigned long long sWv64[2][16];    // exact f64 bits (side slot)

  int oidx[8];
#pragma unroll
  for (int j=0;j<8;++j){
    const int p = t + 1024*j;
    sP[p] = make_float4(X[p*3+0], X[p*3+1], X[p*3+2], 0.f);
    oidx[j] = ord[(size_t)b*NN + 8*t + j];
  }
  if (t < 16){ sW0[0][t]=0ull; sW0[1][t]=0ull; }
  __syncthreads();     // only barrier

  float px[8], py[8], pz[8], thr[8];
  double dd[8];
#pragma unroll
  for (int j=0;j<8;++j){
    const float4 q = sP[oidx[j]];
    px[j]=q.x; py[j]=q.y; pz[j]=q.z;
    dd[j]=1e10;
    thr[j]=fmaf(1e10f, 0x1p-19f, 1e10f);
  }
  // bounding sphere of owned (Morton-adjacent) points, conservative margins
  float ctx=0.f, cty=0.f, ctz=0.f;
#pragma unroll
  for (int j=0;j<8;++j){ ctx+=px[j]; cty+=py[j]; ctz+=pz[j]; }
  ctx*=0.125f; cty*=0.125f; ctz*=0.125f;
  float r2m = 0.f;
#pragma unroll
  for (int j=0;j<8;++j){
    const float ax=px[j]-ctx, ay=py[j]-cty, az=pz[j]-ctz;
    r2m = fmaxf(r2m, fmaf(az,az,fmaf(ay,ay,ax*ax)));
  }
  const float rT = sqrtf(r2m)*(1.0f+0x1p-18f) + 0x1p-20f;

  double tmax = 1e10;
  float  tmax32 = 1e10f;
  int tio = oidx[0], ts = 0;
#pragma unroll
  for (int j=1;j<8;++j) if (oidx[j] < tio){ tio = oidx[j]; ts = j; }
  float skipgate = tmax32*(1.0f+0x1p-14f);

  int f = 0;
  const int lane = t & 63, wid = t >> 6;
  unsigned long long pk_c = 0ull, wv64_c = 0ull;   // cached wave-winner words

  for (int i=0;i<NS-1;++i){
    const int par = i & 1;
    __builtin_amdgcn_s_setprio(1);           // compute phase: favored by CU scheduler
    const float4 cf = sP[f];                 // uniform LDS broadcast
    const float cx=cf.x, cy=cf.y, cz=cf.z;
    if (t == 0){                             // fire-and-forget centroid store
      float* o = newxyz + ((size_t)b*NS + i)*3;
      o[0]=cx; o[1]=cy; o[2]=cz;
    }

    // ---- thread-level conservative skip ----
    const float bx=cx-ctx, by=cy-cty, bz=cz-ctz;
    const float ddc = fmaf(bz,bz,fmaf(by,by,bx*bx));
    const float dcc = sqrtf(ddc);
    float s = dcc - rT; s = s - dcc*0x1p-16f;
    const bool engage = !(s > 0.f && s*s >= skipgate);

    bool lane_changed = false;
    if (engage){
      float e[8]; float mmin = 1e30f;
#pragma unroll
      for (int j=0;j<8;++j){
        const float ax=px[j]-cx, ay=py[j]-cy, az=pz[j]-cz;
        const float d32 = fmaf(az, az, fmaf(ay, ay, ax*ax));
        e[j] = d32 - thr[j];
        mmin = fminf(mmin, e[j]);
      }
      if (__builtin_expect(mmin <= 0.f, 0)){
        const double cxd=(double)cx, cyd=(double)cy, czd=(double)cz;
        bool needscan = false;
#pragma unroll
        for (int j=0;j<8;++j){
          if (e[j] <= 0.f){
            const double d64 = sq3d((double)px[j]-cxd, (double)py[j]-cyd, (double)pz[j]-czd);
            const double nd = fmin(dd[j], d64);
            needscan |= (j == ts) | (nd == tmax);
            dd[j] = nd;
            const float nd32 = (float)nd;
            thr[j] = fmaf(nd32, 0x1p-19f, nd32);
          }
        }
        if (needscan){
          double tm = dd[0]; int io = oidx[0]; int s0 = 0;
#pragma unroll
          for (int j=1;j<8;++j)
            if (dd[j] > tm || (dd[j] == tm && oidx[j] < io)){ tm=dd[j]; io=oidx[j]; s0=j; }
          tmax=tm; tio=io; ts=s0; tmax32=(float)tm;
          skipgate = tmax32*(1.0f+0x1p-14f);
          lane_changed = true;
        }
      }
    }

    // ---- wave winner: full resolve only if some lane changed (else cached) ----
    const unsigned long long chm = __ballot(lane_changed);
    if (chm != 0ull || i == 0){
      const unsigned myb = __float_as_uint(tmax32);
      const unsigned wmx = (unsigned)__builtin_amdgcn_readlane((int)wave_umax63(myb), 63);
      const unsigned long long mask = __ballot(myb == wmx);
      int writer;
      if (__builtin_expect(__popcll(mask) == 1, 1)){
        writer = (int)__builtin_ctzll(mask);
      } else {
        double bestv = -1.0; int bestid = 0x7fffffff;
        unsigned long long mm = mask;
        while (mm){
          const int l = (int)__builtin_ctzll(mm);
          const double v = __shfl(tmax, l);
          const int   id = __shfl(tio, l);
          if (v > bestv || (v == bestv && id < bestid)){ bestv=v; bestid=id; }
          mm &= mm - 1;
        }
        writer = (int)__builtin_ctzll(__ballot(tmax == bestv && tio == bestid));
      }
      // broadcast winner to all lanes; refresh cache (bit-exact wave state)
      wv64_c = (unsigned long long)__double_as_longlong(__shfl(tmax, writer));
      pk_c   = ((unsigned long long)wmx << 32)
             | (unsigned long long)(unsigned)__shfl(tio, writer);
    }
    if (lane == 0){
      sWv64[par][wid] = wv64_c;
      __hip_atomic_store(&sW0[par][wid],
                         pk_c | ((unsigned long long)(unsigned)(i+1) << 13),
                         __ATOMIC_RELEASE, __HIP_MEMORY_SCOPE_WORKGROUP);
    }
    __builtin_amdgcn_s_setprio(0);           // poll phase: yield issue to stragglers

    // ---- flat block reduce: ONE b64 read per lane per poll round ----
    const unsigned want = (unsigned)(i+1);
    unsigned long long w;
    do {
      w = __hip_atomic_load(&sW0[par][lane & 15],
                            __ATOMIC_RELAXED, __HIP_MEMORY_SCOPE_WORKGROUP);
    } while (__ballot((((unsigned)w >> 13) & 1023u) == want) != ~0ull);
    __builtin_amdgcn_fence(__ATOMIC_ACQUIRE, "workgroup");

    const unsigned wf   = (unsigned)(w >> 32);
    const unsigned idxw = (unsigned)w & 8191u;
    const unsigned m32  = grp16_umax(wf);          // block max, all lanes
    const unsigned long long cm = __ballot(wf == m32);
    if (__builtin_expect(__popcll(cm) == 4, 1)){   // unique slot (x4 replicas)
      f = __shfl((int)idxw, (int)__builtin_ctzll(cm));
    } else {
      // rare: exact f64 resolve among f32-bit-tied slots (max value, min index)
      unsigned long long mm = cm & 0xFFFFull;      // one replica set
      double bv = -1.0; int bid = 0x7fffffff;
      while (mm){
        const int l = (int)__builtin_ctzll(mm);
        const double v = __longlong_as_double((long long)sWv64[par][l]); // uniform bcast
        const int   id = __shfl((int)idxw, l);
        if (v > bv || (v == bv && id < bid)){ bv = v; bid = id; }
        mm &= mm - 1;
      }
      f = bid;
    }
  }
  // last centroid
  if (t == 0){
    const float4 cf = sP[f];
    float* o = newxyz + ((size_t)b*NS + (NS-1))*3;
    o[0]=cf.x; o[1]=cf.y; o[2]=cf.z;
  }
}

// ---------------- Ball query: one wave per centroid, f32 screen + f64 band ----------------
__global__ __launch_bounds__(256) void k_ball(const float* __restrict__ xyz,
                                              const float* __restrict__ newxyz,
                                              int* __restrict__ idx){
  const int w = (blockIdx.x << 2) + (threadIdx.x >> 6);  // group id = b*NS+s
  const int lane = threadIdx.x & 63;
  const int b = w >> 9;
  const float* __restrict__ C = newxyz + (size_t)w*3;
  const float cxf=C[0], cyf=C[1], czf=C[2];
  const double cx=(double)cxf, cy=(double)cyf, cz=(double)czf;
  const float* __restrict__ X = xyz + (size_t)b*NN*3;
  int* __restrict__ out = idx + (size_t)w*NK;
  const double R2 = 0.2*0.2;                   // f64: 0.04000000000000000083...
  const float r2lo = 0.04f*(1.0f - 0x1p-16f);  // certain-in  below
  const float r2hi = 0.04f*(1.0f + 0x1p-16f);  // certain-out above
  int count = 0, first = 0;
  for (int base=0; base<NN && count<NK; base+=64){
    const int p = base + lane;
    const float ax=X[p*3+0]-cxf, ay=X[p*3+1]-cyf, az=X[p*3+2]-czf;
    const float d32 = fmaf(az, az, fmaf(ay, ay, ax*ax));
    bool q;
    if (d32 <= r2lo)      q = true;
    else if (d32 > r2hi)  q = false;
    else {                                     // rare band: exact f64 decision
      const double d = sq3d((double)X[p*3+0]-cx, (double)X[p*3+1]-cy, (double)X[p*3+2]-cz);
      q = !(d > R2);
    }
    const unsigned long long m = __ballot(q);
    if (q){
      const int pos = count + __popcll(m & ((1ull<<lane)-1ull));
      if (pos < NK) out[pos] = p;
    }
    if (count == 0 && m) first = base + __builtin_ctzll(m);
    count += __popcll(m);
  }
  if (lane >= count && lane < NK) out[lane] = first;   // pad with first index
}

// ---------------- per-block stats (+optional group min/max) reduction ----------------
__device__ __forceinline__ void stats_reduce(
    float v[4][8], float* __restrict__ sRed, int t, int tp, int tc, int blk,
    int chtot, int choff, bool domm,
    float* __restrict__ pS, float* __restrict__ pQ,
    float* __restrict__ mxp, float* __restrict__ mnp)
{
  __syncthreads();   // sRed overlays earlier smem — ensure all prior reads done
  float S=0.f, Q=0.f;
  for (int m=0;m<4;++m){
#pragma unroll
    for (int i=0;i<8;++i) sRed[tp*68 + tc*8 + i] = v[m][i];
    __syncthreads();
    if (t < 64){
      float mxv = -3.402823466e38f, mnv = 3.402823466e38f;
#pragma unroll
      for (int j=0;j<32;++j){
        const float x = sRed[j*68 + t];
        S += x; Q += x*x;
        mxv = fmaxf(mxv,x); mnv = fminf(mnv,x);
      }
      if (domm){
        const int gg = blk*GPB + m;
        mxp[(size_t)gg*128 + choff + t] = mxv;
        mnp[(size_t)gg*128 + choff + t] = mnv;
      }
    }
    __syncthreads();
  }
  if (t < 64){
    pS[(size_t)blk*chtot + choff + t] = S;
    pQ[(size_t)blk*chtot + choff + t] = Q;
  }
}

// 64-deep inner product accumulate: v[m][i] += sX[pos_m][k]*sW[ch_i][k]
__device__ __forceinline__ void mm64(const float* __restrict__ sXl,
                                     const float* __restrict__ sWl,
                                     int tp, int tc, float v[4][8]){
#pragma unroll 4
  for (int k=0;k<64;++k){
    float xv[4], wv[8];
#pragma unroll
    for (int m=0;m<4;++m) xv[m] = sXl[(tp+32*m)*65 + k];
#pragma unroll
    for (int i=0;i<8;++i) wv[i] = sWl[(tc*8+i)*65 + k];
#pragma unroll
    for (int m=0;m<4;++m)
#pragma unroll
      for (int i=0;i<8;++i) v[m][i] += xv[m]*wv[i];
  }
}

// ---------------- MLP pass: recompute chain to layer DEPTH, emit stats ----------------
template<int DEPTH>
__global__ __launch_bounds__(256) void k_pass(
    const float* __restrict__ xyz, const float* __restrict__ points,
    const float* __restrict__ newxyz, const int* __restrict__ idx,
    const float* __restrict__ w0, const float* __restrict__ b0,
    const float* __restrict__ w1, const float* __restrict__ b1,
    const float* __restrict__ w2, const float* __restrict__ b2,
    const float* __restrict__ ac,
    float* __restrict__ pS, float* __restrict__ pQ,
    float* __restrict__ mxp, float* __restrict__ mnp)
{
  __shared__ float smem[(DEPTH>=1) ? 14784 : 2304];
  float* sX0 = smem;
  float* sW0 = smem + 1024;
  float* sV  = smem + 1600;
  float* sRed= smem;            // overlay
  float* sB2 = smem + 2176;
  float* sW1 = smem + 2304;
  float* sX  = smem + 6464;

  const int t = threadIdx.x;
  const int blk = blockIdx.x;
  const int tc = t & 7, tp = t >> 3;

  // stage weights / params
  for (int i=t;i<384;i+=256) sW0[(i/6)*9 + (i%6)] = w0[i];
  if (t < 64) sV[t] = b0[t];
  if constexpr (DEPTH >= 1){
    if (t < 64){ sV[64+t]=ac[t]; sV[128+t]=ac[64+t]; sV[192+t]=b1[t]; }
    for (int i=t;i<4096;i+=256) sW1[(i>>6)*65 + (i&63)] = w1[i];
  }
  if constexpr (DEPTH == 2){
    if (t < 64){ sV[256+t]=ac[128+t]; sV[320+t]=ac[192+t]; }
    if (t < 128) sB2[t] = b2[t];
  }

  // gather -> x0 (6 ch): [gxyz - centroid, gpts]
  {
    const int pos = t & 127;
    const int gg = blk*GPB + (pos >> 5);
    const int b  = gg >> 9;
    const int id = idx[gg*NK + (pos & 31)];
    if (t < 128){
      const float* __restrict__ P = xyz + ((size_t)b*NN + id)*3;
      const float* __restrict__ C = newxyz + (size_t)gg*3;
      sX0[pos*8+0] = P[0]-C[0];
      sX0[pos*8+1] = P[1]-C[1];
      sX0[pos*8+2] = P[2]-C[2];
    } else {
      const float* __restrict__ P = points + ((size_t)b*NN + id)*3;
      sX0[pos*8+3] = P[0];
      sX0[pos*8+4] = P[1];
      sX0[pos*8+5] = P[2];
    }
  }
  __syncthreads();

  // y0 = W0 x0 + b0   (thread: 4 positions x 8 channels)
  float v[4][8];
#pragma unroll
  for (int m=0;m<4;++m){
    const int pos = tp + 32*m;
    float xr[6];
#pragma unroll
    for (int c=0;c<6;++c) xr[c] = sX0[pos*8+c];
#pragma unroll
    for (int i=0;i<8;++i){
      const int ch = tc*8+i;
      float acc = sV[ch];
#pragma unroll
      for (int c=0;c<6;++c) acc += sW0[ch*9+c]*xr[c];
      v[m][i] = acc;
    }
  }

  if constexpr (DEPTH == 0){
    stats_reduce(v, sRed, t, tp, tc, blk, 64, 0, false, pS, pQ, mxp, mnp);
    return;
  } else {
    // x1 = relu(a0*y0 + c0)
#pragma unroll
    for (int m=0;m<4;++m){
      const int pos = tp + 32*m;
#pragma unroll
      for (int i=0;i<8;++i){
        const int ch = tc*8+i;
        sX[pos*65+ch] = fmaxf(sV[64+ch]*v[m][i] + sV[128+ch], 0.f);
      }
    }
    __syncthreads();
    // y1 = W1 x1 + b1
#pragma unroll
    for (int m=0;m<4;++m)
#pragma unroll
      for (int i=0;i<8;++i) v[m][i] = sV[192 + tc*8 + i];
    mm64(sX, sW1, tp, tc, v);

    if constexpr (DEPTH == 1){
      stats_reduce(v, sRed, t, tp, tc, blk, 64, 0, false, pS, pQ, mxp, mnp);
      return;
    } else {
      __syncthreads();
      // x2 = relu(a1*y1 + c1), overwrite sX
#pragma unroll
      for (int m=0;m<4;++m){
        const int pos = tp + 32*m;
#pragma unroll
        for (int i=0;i<8;++i){
          const int ch = tc*8+i;
          sX[pos*65+ch] = fmaxf(sV[256+ch]*v[m][i] + sV[320+ch], 0.f);
        }
      }
      __syncthreads();
      // y2 = W2 x2 + b2 in two 64-channel chunks (W2 chunk reuses sW1 space)
      for (int o=0;o<2;++o){
        for (int i=t;i<4096;i+=256) sW1[(i>>6)*65 + (i&63)] = w2[o*4096 + i];
        __syncthreads();
#pragma unroll
        for (int m=0;m<4;++m)
#pragma unroll
          for (int i=0;i<8;++i) v[m][i] = sB2[o*64 + tc*8 + i];
        mm64(sX, sW1, tp, tc, v);
        stats_reduce(v, sRed, t, tp, tc, blk, 128, o*64, true, pS, pQ, mxp, mnp);
      }
      return;
    }
  }
}

// ---------------- pass1 + store y1 (bf16) for the cached pass2 path ----------------
__global__ __launch_bounds__(256) void k_pass1s(
    const float* __restrict__ xyz, const float* __restrict__ points,
    const float* __restrict__ newxyz, const int* __restrict__ idx,
    const float* __restrict__ w0, const float* __restrict__ b0,
    const float* __restrict__ w1, const float* __restrict__ b1,
    const float* __restrict__ ac, unsigned* __restrict__ y1c,
    float* __restrict__ pS, float* __restrict__ pQ,
    float* __restrict__ mxp, float* __restrict__ mnp)
{
  __shared__ float smem[14784];
  float* sX0 = smem;
  float* sW0 = smem + 1024;
  float* sV  = smem + 1600;
  float* sRed= smem;
  float* sW1 = smem + 2304;
  float* sX  = smem + 6464;

  const int t = threadIdx.x;
  const int blk = blockIdx.x;
  const int tc = t & 7, tp = t >> 3;

  for (int i=t;i<384;i+=256) sW0[(i/6)*9 + (i%6)] = w0[i];
  if (t < 64){ sV[t]=b0[t]; sV[64+t]=ac[t]; sV[128+t]=ac[64+t]; sV[192+t]=b1[t]; }
  for (int i=t;i<4096;i+=256) sW1[(i>>6)*65 + (i&63)] = w1[i];

  {
    const int pos = t & 127;
    const int gg = blk*GPB + (pos >> 5);
    const int b  = gg >> 9;
    const int id = idx[gg*NK + (pos & 31)];
    if (t < 128){
      const float* __restrict__ P = xyz + ((size_t)b*NN + id)*3;
      const float* __restrict__ C = newxyz + (size_t)gg*3;
      sX0[pos*8+0] = P[0]-C[0];
      sX0[pos*8+1] = P[1]-C[1];
      sX0[pos*8+2] = P[2]-C[2];
    } else {
      const float* __restrict__ P = points + ((size_t)b*NN + id)*3;
      sX0[pos*8+3] = P[0];
      sX0[pos*8+4] = P[1];
      sX0[pos*8+5] = P[2];
    }
  }
  __syncthreads();

  float v[4][8];
#pragma unroll
  for (int m=0;m<4;++m){
    const int pos = tp + 32*m;
    float xr[6];
#pragma unroll
    for (int c=0;c<6;++c) xr[c] = sX0[pos*8+c];
#pragma unroll
    for (int i=0;i<8;++i){
      const int ch = tc*8+i;
      float acc = sV[ch];
#pragma unroll
      for (int c=0;c<6;++c) acc += sW0[ch*9+c]*xr[c];
      v[m][i] = acc;
    }
  }
  // x1 = relu(a0*y0 + c0)
#pragma unroll
  for (int m=0;m<4;++m){
    const int pos = tp + 32*m;
#pragma unroll
    for (int i=0;i<8;++i){
      const int ch = tc*8+i;
      sX[pos*65+ch] = fmaxf(sV[64+ch]*v[m][i] + sV[128+ch], 0.f);
    }
  }
  __syncthreads();
  // y1 = W1 x1 + b1
#pragma unroll
  for (int m=0;m<4;++m)
#pragma unroll
    for (int i=0;i<8;++i) v[m][i] = sV[192 + tc*8 + i];
  mm64(sX, sW1, tp, tc, v);

  // store y1 as bf16: per pos, 64 ch = 8 uint4 slots; this thread owns slot tc
#pragma unroll
  for (int m=0;m<4;++m){
    const int pos = tp + 32*m;
    uint4 pk;
    pk.x = bf2pk(v[m][0], v[m][1]);
    pk.y = bf2pk(v[m][2], v[m][3]);
    pk.z = bf2pk(v[m][4], v[m][5]);
    pk.w = bf2pk(v[m][6], v[m][7]);
    ((uint4*)y1c)[((size_t)blk*128 + pos)*8 + tc] = pk;
  }

  stats_reduce(v, sRed, t, tp, tc, blk, 64, 0, false, pS, pQ, mxp, mnp);
}

// ---------------- pass2 from cached y1 (bf16): x2=relu(a1*y1+c1); layer2 ----------------
__global__ __launch_bounds__(256) void k_pass2l(
    const unsigned* __restrict__ y1c,
    const float* __restrict__ w2, const float* __restrict__ b2,
    const float* __restrict__ ac,
    float* __restrict__ pS, float* __restrict__ pQ,
    float* __restrict__ mxp, float* __restrict__ mnp)
{
  __shared__ float smem[14784];
  float* sV  = smem + 1600;
  float* sRed= smem;
  float* sB2 = smem + 2176;
  float* sW1 = smem + 2304;
  float* sX  = smem + 6464;

  const int t = threadIdx.x;
  const int blk = blockIdx.x;
  const int tc = t & 7, tp = t >> 3;

  if (t < 64){ sV[t]=ac[128+t]; sV[64+t]=ac[192+t]; }   // a1, c1
  if (t < 128) sB2[t] = b2[t];

  // load y1 (bf16) for this block's 128 positions
  float v[4][8];
#pragma unroll
  for (int m=0;m<4;++m){
    const int pos = tp + 32*m;
    const uint4 pk = ((const uint4*)y1c)[((size_t)blk*128 + pos)*8 + tc];
    v[m][0]=bflo(pk.x); v[m][1]=bfhi(pk.x);
    v[m][2]=bflo(pk.y); v[m][3]=bfhi(pk.y);
    v[m][4]=bflo(pk.z); v[m][5]=bfhi(pk.z);
    v[m][6]=bflo(pk.w); v[m][7]=bfhi(pk.w);
  }
  __syncthreads();   // sV/sB2 ready

  // x2 = relu(a1*y1 + c1)
#pragma unroll
  for (int m=0;m<4;++m){
    const int pos = tp + 32*m;
#pragma unroll
    for (int i=0;i<8;++i){
      const int ch = tc*8+i;
      sX[pos*65+ch] = fmaxf(sV[ch]*v[m][i] + sV[64+ch], 0.f);
    }
  }
  __syncthreads();

  for (int o=0;o<2;++o){
    for (int i2=t;i2<4096;i2+=256) sW1[(i2>>6)*65 + (i2&63)] = w2[o*4096 + i2];
    __syncthreads();
#pragma unroll
    for (int m=0;m<4;++m)
#pragma unroll
      for (int i=0;i<8;++i) v[m][i] = sB2[o*64 + tc*8 + i];
    mm64(sX, sW1, tp, tc, v);
    stats_reduce(v, sRed, t, tp, tc, blk, 128, o*64, true, pS, pQ, mxp, mnp);
  }
}

// ---------------- stats stage 1: 16 blocks, each sums NBLK/16 partial rows ----------------
__global__ __launch_bounds__(1024) void k_stats1(const float* __restrict__ pS,
                                                 const float* __restrict__ pQ,
                                                 float* __restrict__ pP, int CH){
  __shared__ float sS[1024], sQ[1024];
  const int t = threadIdx.x, blk = blockIdx.x;
  const int ch = t & (CH-1);
  const int seg = t / CH;
  const int SEG = 1024 / CH;                 // 16 (CH=64) or 8 (CH=128)
  const int rows = (NBLK/SBLK) / SEG;        // 8 or 16
  const int j0 = blk*(NBLK/SBLK) + seg*rows;
  float S=0.f, Q=0.f;
#pragma unroll 4
  for (int r=0;r<rows;++r){
    const size_t o = (size_t)(j0+r)*CH + ch;
    S += pS[o]; Q += pQ[o];
  }
  sS[t]=S; sQ[t]=Q;
  __syncthreads();
  if (t < CH){
    float aS=0.f, aQ=0.f;
    for (int s2=0;s2<SEG;++s2){ aS += sS[s2*CH+ch]; aQ += sQ[s2*CH+ch]; }
    pP[(size_t)blk*2*CH + ch]      = aS;
    pP[(size_t)blk*2*CH + CH + ch] = aQ;
  }
}

// ---------------- stats stage 2: fold 16 partials, derive a,c ----------------
__global__ __launch_bounds__(128) void k_stats2(const float* __restrict__ pP,
                                                const float* __restrict__ g,
                                                const float* __restrict__ beta,
                                                float* __restrict__ a, float* __restrict__ c,
                                                int CH){
  const int ch = threadIdx.x;
  if (ch >= CH) return;
  float S=0.f, Q=0.f;
#pragma unroll
  for (int k=0;k<SBLK;++k){
    S += pP[(size_t)k*2*CH + ch];
    Q += pP[(size_t)k*2*CH + CH + ch];
  }
  const float mean = S * (1.f/(float)NPOSI);
  const float var  = fmaxf(Q * (1.f/(float)NPOSI) - mean*mean, 0.f);
  const float av = g[ch] * rsqrtf(var + 1e-5f);
  a[ch] = av;
  c[ch] = beta[ch] - mean*av;
}

// ---------------- final: BN+ReLU applied to pooled value ----------------
__global__ __launch_bounds__(256) void k_final(const float* __restrict__ mxp, const float* __restrict__ mnp,
                                               const float* __restrict__ a, const float* __restrict__ c,
                                               float* __restrict__ out){
  const int i = blockIdx.x*256 + threadIdx.x;
  const int ch = i & 127;
  const float av = a[ch], cv = c[ch];
  const float vv = (av >= 0.f) ? mxp[i] : mnp[i];   // relu∘affine is monotone
  out[i] = fmaxf(av*vv + cv, 0.f);
}

extern "C" void kernel_launch(void* const* d_in, const int* in_sizes, int n_in,
                              void* d_out, int out_size, void* d_ws, size_t ws_size,
                              hipStream_t stream){
  (void)in_sizes; (void)n_in; (void)out_size;
  const float* xyz    = (const float*)d_in[0];
  const float* points = (const float*)d_in[1];
  const float* w0 = (const float*)d_in[2];
  const float* b0 = (const float*)d_in[3];
  const float* g0 = (const float*)d_in[4];
  const float* be0= (const float*)d_in[5];
  const float* w1 = (const float*)d_in[6];
  const float* b1 = (const float*)d_in[7];
  const float* g1 = (const float*)d_in[8];
  const float* be1= (const float*)d_in[9];
  const float* w2 = (const float*)d_in[10];
  const float* b2 = (const float*)d_in[11];
  const float* g2 = (const float*)d_in[12];
  const float* be2= (const float*)d_in[13];

  float* out_newxyz = (float*)d_out;
  float* out_newpts = out_newxyz + (size_t)NB*NS*3;

  char* ws = (char*)d_ws;
  int*   idx = (int*)ws;                              // 1 MiB (ord overlays first 512KB)
  float* ac  = (float*)(ws + (1u<<20));               // 512 floats
  float* pS  = (float*)(ws + (1u<<20) + 4096);        // 2048*128 f
  float* pQ  = pS + (size_t)NBLK*128;                 // 2048*128 f
  float* mxp = pQ + (size_t)NBLK*128;                 // 8192*128 f
  float* mnp = mxp + (size_t)NG*128;                  // 8192*128 f
  float* pP  = mnp + (size_t)NG*128;                  // 16*2*128 f = 16KB
  unsigned* y1c = (unsigned*)(pP + (size_t)SBLK*2*128);  // 262144*64 bf16 = 33.5MB
  const size_t need_small = (1u<<20) + 4096 + (size_t)2*NBLK*128*4 + (size_t)2*NG*128*4
                          + (size_t)SBLK*2*128*4;
  const size_t need_big   = need_small + (size_t)NPOSI*64*2;
  if (ws_size < need_small) return;
  const bool big = (ws_size >= need_big);

  int* ord = idx;   // reuse: written by k_morton, read by k_fps, then overwritten by k_ball

  k_morton<<<NB, 1024, 0, stream>>>(xyz, ord);
  k_fps  <<<NB, 1024, 0, stream>>>(xyz, ord, out_newxyz);
  k_ball <<<NG/4, 256, 0, stream>>>(xyz, out_newxyz, idx);

  k_pass<0><<<NBLK,256,0,stream>>>(xyz,points,out_newxyz,idx,w0,b0,w1,b1,w2,b2,ac,pS,pQ,mxp,mnp);
  k_stats1<<<SBLK,1024,0,stream>>>(pS,pQ,pP,64);
  k_stats2<<<1,128,0,stream>>>(pP,g0,be0, ac+0,   ac+64,  64);
  if (big){
    k_pass1s<<<NBLK,256,0,stream>>>(xyz,points,out_newxyz,idx,w0,b0,w1,b1,ac,y1c,pS,pQ,mxp,mnp);
    k_stats1<<<SBLK,1024,0,stream>>>(pS,pQ,pP,64);
    k_stats2<<<1,128,0,stream>>>(pP,g1,be1, ac+128, ac+192, 64);
    k_pass2l<<<NBLK,256,0,stream>>>(y1c,w2,b2,ac,pS,pQ,mxp,mnp);
  } else {
    k_pass<1><<<NBLK,256,0,stream>>>(xyz,points,out_newxyz,idx,w0,b0,w1,b1,w2,b2,ac,pS,pQ,mxp,mnp);
    k_stats1<<<SBLK,1024,0,stream>>>(pS,pQ,pP,64);
    k_stats2<<<1,128,0,stream>>>(pP,g1,be1, ac+128, ac+192, 64);
    k_pass<2><<<NBLK,256,0,stream>>>(xyz,points,out_newxyz,idx,w0,b0,w1,b1,w2,b2,ac,pS,pQ,mxp,mnp);
  }
  k_stats1<<<SBLK,1024,0,stream>>>(pS,pQ,pP,128);
  k_stats2<<<1,128,0,stream>>>(pP,g2,be2, ac+256, ac+384, 128);
  k_final<<<(NG*128)/256,256,0,stream>>>(mxp,mnp,ac+256,ac+384,out_newpts);
}